// Round 13
// baseline (208.180 us; speedup 1.0000x reference)
//
#include <hip/hip_runtime.h>
#include <hip/hip_bf16.h>

// N=20000 nodes, E=200000 edges, H=8, C=256, IN=256, OUT=250, H*C=2048.
// R13: alphaz = 1 wave/dst, 2 edges across half-waves (uint4 loads, 8ch/lane,
//      self edge folded in as edge #deg); gemm<2>+gemm<1> fused (stage 2 reads
//      L2-hot Hf written by the same block).

typedef __attribute__((ext_vector_type(8))) short short8v;
typedef __attribute__((ext_vector_type(4))) float float4v;

__device__ __forceinline__ unsigned f2bfu(float f) {
  unsigned u = __float_as_uint(f);
  return (u + 0x7fffu + ((u >> 16) & 1u)) >> 16;  // RNE f32 -> bf16
}
__device__ __forceinline__ float bfu_lo(unsigned u) { return __uint_as_float(u << 16); }
__device__ __forceinline__ float bfu_hi(unsigned u) { return __uint_as_float(u & 0xffff0000u); }
__device__ __forceinline__ unsigned pack2(float a, float b) { return f2bfu(a) | (f2bfu(b) << 16); }

__device__ __forceinline__ void ld8(const float* p, float* v) {
  float4 a = ((const float4*)p)[0], b = ((const float4*)p)[1];
  v[0] = a.x; v[1] = a.y; v[2] = a.z; v[3] = a.w;
  v[4] = b.x; v[5] = b.y; v[6] = b.z; v[7] = b.w;
}

__device__ __forceinline__ float bcast(float x, int e) {
  return __uint_as_float((unsigned)__builtin_amdgcn_readlane((int)__float_as_uint(x), e));
}

__device__ __forceinline__ void gll16(const void* g, void* l) {
  __builtin_amdgcn_global_load_lds(
      (__attribute__((address_space(1))) void*)const_cast<void*>(g),
      (__attribute__((address_space(3))) void*)(l), 16, 0, 0);
}

// ---------------- prep1: transpose(W_lin) + prepws + hist ----------------
__global__ __launch_bounds__(256) void prep1_kernel(
    const float* __restrict__ W_lin, short* __restrict__ wlT,
    const float* __restrict__ W, const float* __restrict__ att_s,
    const float* __restrict__ att_d, float* __restrict__ ws_s,
    float* __restrict__ ws_d, float* __restrict__ ws_r,
    const int* __restrict__ ei, int* __restrict__ deg) {
  __shared__ float smem[4096];
  int b = blockIdx.x;
  int t = threadIdx.x;
  if (b < 64) {
    float (*tile)[33] = (float(*)[33])smem;
    int tx = t & 31, ty = t >> 5;
    int c0 = (b & 7) * 32, r0 = (b >> 3) * 32;
    #pragma unroll
    for (int j = ty; j < 32; j += 8) {
      int r = r0 + j, c = c0 + tx;
      tile[j][tx] = (c < 250) ? W_lin[(size_t)r * 250 + c] : 0.f;
    }
    __syncthreads();
    #pragma unroll
    for (int j = ty; j < 32; j += 8) {
      int c = c0 + j, r = r0 + tx;
      wlT[(size_t)c * 256 + r] = (short)f2bfu(tile[tx][j]);
    }
  } else if (b < 96) {
    float* sas = smem;
    float* sad = smem + 2048;
    for (int i = t; i < 2048; i += 256) { sas[i] = att_s[i]; sad[i] = att_d[i]; }
    __syncthreads();
    int kk = t >> 5, h = (t >> 2) & 7, q = t & 3;
    int k = (b - 64) * 8 + kk;
    const float4* wr = (const float4*)(W + (size_t)k * 2048 + h * 256 + q * 64);
    const float* as = sas + h * 256 + q * 64;
    const float* ad = sad + h * 256 + q * 64;
    float s = 0.f, dd = 0.f, r = 0.f;
    #pragma unroll
    for (int c4 = 0; c4 < 16; ++c4) {
      float4 wv = wr[c4];
      int c = c4 * 4;
      s  += wv.x * as[c] + wv.y * as[c + 1] + wv.z * as[c + 2] + wv.w * as[c + 3];
      dd += wv.x * ad[c] + wv.y * ad[c + 1] + wv.z * ad[c + 2] + wv.w * ad[c + 3];
      r  += wv.x + wv.y + wv.z + wv.w;
    }
    #pragma unroll
    for (int off = 1; off < 4; off <<= 1) {
      s += __shfl_xor(s, off);
      dd += __shfl_xor(dd, off);
      r += __shfl_xor(r, off);
    }
    if (q == 0) {
      int g = k * 8 + h;
      ws_s[g] = s;
      ws_d[g] = dd;
      ws_r[g] = r;
    }
  } else {
    int e = (b - 96) * 256 + t;
    if (e < 200000) atomicAdd(&deg[ei[200000 + e]], 1);
  }
}

// a_s/a_d/rs + coalesced x_bf (thread (node,h) owns chunks 8h..8h+7)
__global__ __launch_bounds__(256) void asd_kernel(const float* __restrict__ x,
    const float* __restrict__ ws_s, const float* __restrict__ ws_d,
    const float* __restrict__ ws_r, float* __restrict__ a_s,
    float* __restrict__ a_d, float* __restrict__ rs, short* __restrict__ x_bf) {
  __shared__ float ls[2048], ld2[2048], lr[2048];
  int tid = threadIdx.x;
  for (int i = tid; i < 2048; i += 256) { ls[i] = ws_s[i]; ld2[i] = ws_d[i]; lr[i] = ws_r[i]; }
  __syncthreads();
  int node = blockIdx.x * 32 + (tid >> 3);
  int h = tid & 7;
  const float4* xr = (const float4*)(x + (size_t)node * 256);
  float as = 0.f, ad = 0.f, rr = 0.f;
  #pragma unroll 1
  for (int g = 0; g < 8; ++g) {
    bool own = (g == h);
    int bufi[16];
    #pragma unroll
    for (int j = 0; j < 8; ++j) {
      int k4 = g * 8 + j;
      float4 v = xr[k4];
      int k8 = k4 * 32 + h;
      as += v.x * ls[k8] + v.y * ls[k8 + 8] + v.z * ls[k8 + 16] + v.w * ls[k8 + 24];
      ad += v.x * ld2[k8] + v.y * ld2[k8 + 8] + v.z * ld2[k8 + 16] + v.w * ld2[k8 + 24];
      rr += v.x * lr[k8] + v.y * lr[k8 + 8] + v.z * lr[k8 + 16] + v.w * lr[k8 + 24];
      bufi[2 * j] = (int)pack2(v.x, v.y);
      bufi[2 * j + 1] = (int)pack2(v.z, v.w);
    }
    if (own) {
      int4* dst = (int4*)(x_bf + (size_t)node * 256 + h * 32);
      dst[0] = make_int4(bufi[0], bufi[1], bufi[2], bufi[3]);
      dst[1] = make_int4(bufi[4], bufi[5], bufi[6], bufi[7]);
      dst[2] = make_int4(bufi[8], bufi[9], bufi[10], bufi[11]);
      dst[3] = make_int4(bufi[12], bufi[13], bufi[14], bufi[15]);
    }
  }
  a_s[node * 8 + h] = as;
  a_d[node * 8 + h] = ad;
  rs[node * 8 + h] = rr;
}

// ---------------- fused double GEMM ----------------
// Stage 1: Hf = relu(u @ wmixT^T + fb + x)   [M x 256] bf16  (K=2048)
// Stage 2: out = Hf @ wlT^T + b_lin          [M x 250] f32   (K=256, L2-hot A)
__global__ __launch_bounds__(256, 2) void gemm_fused_kernel(
    const short* __restrict__ u, const short* __restrict__ wmixT,
    const short* __restrict__ wlT, short* __restrict__ Hf,
    float* __restrict__ out, const float* __restrict__ fb,
    const float* __restrict__ x, const float* __restrict__ b_lin, int M) {
  __shared__ short lA[64 * 128];    // 16 KB
  __shared__ short lB[256 * 128];   // 64 KB
  int tid = threadIdx.x;
  int wave = tid >> 6, lane = tid & 63;
  int m0 = blockIdx.x << 6;
  int lr = lane & 15, lq = lane >> 4;
  int lrow4 = lane >> 4;
  int pch = lane & 15;

  float4v acc[4][4];
  #pragma unroll
  for (int i = 0; i < 4; ++i)
    #pragma unroll
    for (int j = 0; j < 4; ++j) acc[i][j] = (float4v){0.f, 0.f, 0.f, 0.f};

  int rowlA[4], growA[4], logA[4];
  #pragma unroll
  for (int it = 0; it < 4; ++it) {
    rowlA[it] = wave * 16 + it * 4 + lrow4;
    int grow = m0 + rowlA[it];
    if (grow >= M) grow = M - 1;
    growA[it] = grow;
    logA[it] = pch ^ (rowlA[it] & 7);
  }
  int rowB[16], logB[16];
  #pragma unroll
  for (int it = 0; it < 16; ++it) {
    rowB[it] = wave * 64 + it * 4 + lrow4;
    logB[it] = pch ^ (rowB[it] & 7);
  }

  // ---- stage 1: K=2048 ----
  for (int t = 0; t < 16; ++t) {
    int k0 = t << 7;
    __syncthreads();
    #pragma unroll
    for (int it = 0; it < 4; ++it)
      gll16(u + (size_t)growA[it] * 2048 + logA[it] * 8 + k0, lA + (wave * 16 + it * 4) * 128);
    #pragma unroll
    for (int it = 0; it < 16; ++it)
      gll16(wmixT + (size_t)rowB[it] * 2048 + logB[it] * 8 + k0, lB + (wave * 64 + it * 4) * 128);
    __syncthreads();
    #pragma unroll
    for (int ks = 0; ks < 4; ++ks) {
      int phys = ((ks * 4 + lq) ^ (lr & 7)) * 8;
      short8v af[4], bfv[4];
      #pragma unroll
      for (int i = 0; i < 4; ++i)
        af[i] = *(const short8v*)(lA + (i * 16 + lr) * 128 + phys);
      #pragma unroll
      for (int j = 0; j < 4; ++j)
        bfv[j] = *(const short8v*)(lB + (wave * 64 + j * 16 + lr) * 128 + phys);
      #pragma unroll
      for (int i = 0; i < 4; ++i)
        #pragma unroll
        for (int j = 0; j < 4; ++j)
          acc[i][j] = __builtin_amdgcn_mfma_f32_16x16x32_bf16(af[i], bfv[j], acc[i][j], 0, 0, 0);
    }
  }
  // stage-1 epilogue: Hf = relu(acc + fb + x), bf16
  #pragma unroll
  for (int i = 0; i < 4; ++i) {
    #pragma unroll
    for (int jj = 0; jj < 4; ++jj) {
      int row = m0 + i * 16 + lq * 4 + jj;
      if (row >= M) continue;
      #pragma unroll
      for (int j = 0; j < 4; ++j) {
        int col = wave * 64 + j * 16 + lr;
        float o = acc[i][j][jj] + fb[col] + x[(size_t)row * 256 + col];
        Hf[(size_t)row * 256 + col] = (short)f2bfu(fmaxf(o, 0.f));
      }
    }
  }

  // ---- stage 2: out = Hf @ wlT^T + b_lin, K=256 ----
  #pragma unroll
  for (int i = 0; i < 4; ++i)
    #pragma unroll
    for (int j = 0; j < 4; ++j) acc[i][j] = (float4v){0.f, 0.f, 0.f, 0.f};

  for (int t = 0; t < 2; ++t) {
    int k0 = t << 7;
    __syncthreads();   // drains vmcnt: stage-1 stores visible; LDS safe to overwrite
    #pragma unroll
    for (int it = 0; it < 4; ++it)
      gll16(Hf + (size_t)growA[it] * 256 + logA[it] * 8 + k0, lA + (wave * 16 + it * 4) * 128);
    #pragma unroll
    for (int it = 0; it < 16; ++it)
      gll16(wlT + (size_t)rowB[it] * 256 + logB[it] * 8 + k0, lB + (wave * 64 + it * 4) * 128);
    __syncthreads();
    #pragma unroll
    for (int ks = 0; ks < 4; ++ks) {
      int phys = ((ks * 4 + lq) ^ (lr & 7)) * 8;
      short8v af[4], bfv[4];
      #pragma unroll
      for (int i = 0; i < 4; ++i)
        af[i] = *(const short8v*)(lA + (i * 16 + lr) * 128 + phys);
      #pragma unroll
      for (int j = 0; j < 4; ++j)
        bfv[j] = *(const short8v*)(lB + (wave * 64 + j * 16 + lr) * 128 + phys);
      #pragma unroll
      for (int i = 0; i < 4; ++i)
        #pragma unroll
        for (int j = 0; j < 4; ++j)
          acc[i][j] = __builtin_amdgcn_mfma_f32_16x16x32_bf16(af[i], bfv[j], acc[i][j], 0, 0, 0);
    }
  }
  #pragma unroll
  for (int i = 0; i < 4; ++i) {
    #pragma unroll
    for (int jj = 0; jj < 4; ++jj) {
      int row = m0 + i * 16 + lq * 4 + jj;
      if (row >= M) continue;
      #pragma unroll
      for (int j = 0; j < 4; ++j) {
        int col = wave * 64 + j * 16 + lr;
        if (col < 250) out[(size_t)row * 250 + col] = acc[i][j][jj] + b_lin[col];
      }
    }
  }
}

// ---------------- CSR scan / scatter ----------------

__global__ __launch_bounds__(1024) void scan_kernel(const int* __restrict__ deg,
                                                    int* __restrict__ rowptr,
                                                    int* __restrict__ cursor, int n) {
  __shared__ int part[1024];
  int t = threadIdx.x;
  int base = t * 20;
  int loc[20];
  int run = 0;
  #pragma unroll
  for (int j = 0; j < 20; ++j) {
    int idx = base + j;
    int v = (idx < n) ? deg[idx] : 0;
    loc[j] = run;
    run += v;
  }
  part[t] = run;
  __syncthreads();
  for (int off = 1; off < 1024; off <<= 1) {
    int add = (t >= off) ? part[t - off] : 0;
    __syncthreads();
    part[t] += add;
    __syncthreads();
  }
  int off0 = (t > 0) ? part[t - 1] : 0;
  #pragma unroll
  for (int j = 0; j < 20; ++j) {
    int idx = base + j;
    if (idx < n) {
      int v = off0 + loc[j];
      rowptr[idx] = v;
      cursor[idx] = v;
    }
  }
  if (t == 1023) rowptr[n] = part[1023];
}

__global__ void scatter_kernel(const int* __restrict__ ei, int* __restrict__ cursor,
                               int* __restrict__ csr_src, int E) {
  int e = blockIdx.x * 256 + threadIdx.x;
  if (e < E) {
    int pos = atomicAdd(&cursor[ei[E + e]], 1);
    csr_src[pos] = ei[e];
  }
}

// ---------------- fused softmax + z-aggregate (1 wave/dst, 2 edges via half-waves) ----
// No-max softmax, deferred normalization. Self edge = edge #deg (src=d).
// u[d][h*256+c] = (1/s_h) sum_e ex_eh x_bf[src_e][c]; pp[d][h] = (1/s_h) sum ex*rs.
__global__ __launch_bounds__(256) void alphaz_kernel(
    const short* __restrict__ x_bf, const float* __restrict__ a_s,
    const float* __restrict__ a_d, const float* __restrict__ rs,
    const int* __restrict__ rowptr, const int* __restrict__ csr,
    short* __restrict__ u, float* __restrict__ pp) {
  int d = blockIdx.x * 4 + (threadIdx.x >> 6);
  int lane = threadIdx.x & 63;
  int half = lane >> 5;
  int cl = (lane & 31) * 8;       // 8 channels per lane
  int beg = rowptr[d];
  int deg = rowptr[d + 1] - beg;
  int nb = deg + 1;               // + self at index deg

  float ad8[8];
  ld8(a_d + (size_t)d * 8, ad8);

  float acc[8][8];
  #pragma unroll
  for (int h = 0; h < 8; ++h)
    #pragma unroll
    for (int c = 0; c < 8; ++c) acc[h][c] = 0.f;
  float s8[8] = {0, 0, 0, 0, 0, 0, 0, 0};
  float p8[8] = {0, 0, 0, 0, 0, 0, 0, 0};

  for (int base = 0; base < nb; base += 64) {
    int i = base + lane;
    bool act = i < nb;
    int srcv = d;                 // self (i==deg) and inactive default
    if (i < deg) srcv = csr[beg + i];
    float ex[8];
    {
      float t8[8], r8[8];
      ld8(a_s + (size_t)srcv * 8, t8);
      ld8(rs + (size_t)srcv * 8, r8);
      #pragma unroll
      for (int h = 0; h < 8; ++h) {
        float e = t8[h] + ad8[h];
        e = (e > 0.f) ? e : 0.2f * e;
        float xx = act ? __expf(e) : 0.f;
        ex[h] = xx;
        s8[h] += xx;
        p8[h] += xx * r8[h];
      }
    }
    int cnt = nb - base;
    if (cnt > 64) cnt = 64;
    int e = 0;
    for (; e + 1 < cnt; e += 2) {
      int s0 = __builtin_amdgcn_readlane(srcv, e);
      int s1 = __builtin_amdgcn_readlane(srcv, e + 1);
      int ss = half ? s1 : s0;
      uint4 v = *(const uint4*)(x_bf + (size_t)ss * 256 + cl);
      float q[8];
      #pragma unroll
      for (int h = 0; h < 8; ++h) {
        float qa = bcast(ex[h], e), qb = bcast(ex[h], e + 1);
        q[h] = half ? qb : qa;
      }
      float xv[8];
      xv[0] = bfu_lo(v.x); xv[1] = bfu_hi(v.x);
      xv[2] = bfu_lo(v.y); xv[3] = bfu_hi(v.y);
      xv[4] = bfu_lo(v.z); xv[5] = bfu_hi(v.z);
      xv[6] = bfu_lo(v.w); xv[7] = bfu_hi(v.w);
      #pragma unroll
      for (int h = 0; h < 8; ++h)
        #pragma unroll
        for (int c = 0; c < 8; ++c) acc[h][c] += q[h] * xv[c];
    }
    if (e < cnt) {
      int s0 = __builtin_amdgcn_readlane(srcv, e);
      uint4 v = *(const uint4*)(x_bf + (size_t)s0 * 256 + cl);
      float q[8];
      #pragma unroll
      for (int h = 0; h < 8; ++h) q[h] = half ? 0.f : bcast(ex[h], e);
      float xv[8];
      xv[0] = bfu_lo(v.x); xv[1] = bfu_hi(v.x);
      xv[2] = bfu_lo(v.y); xv[3] = bfu_hi(v.y);
      xv[4] = bfu_lo(v.z); xv[5] = bfu_hi(v.z);
      xv[6] = bfu_lo(v.w); xv[7] = bfu_hi(v.w);
      #pragma unroll
      for (int h = 0; h < 8; ++h)
        #pragma unroll
        for (int c = 0; c < 8; ++c) acc[h][c] += q[h] * xv[c];
    }
  }

  // combine the two halves (same channels, alternating edges)
  #pragma unroll
  for (int h = 0; h < 8; ++h)
    #pragma unroll
    for (int c = 0; c < 8; ++c) acc[h][c] += __shfl_xor(acc[h][c], 32);
  // s/p reduce across all 64 lanes
  #pragma unroll
  for (int off = 1; off < 64; off <<= 1)
    #pragma unroll
    for (int h = 0; h < 8; ++h) {
      s8[h] += __shfl_xor(s8[h], off);
      p8[h] += __shfl_xor(p8[h], off);
    }
  float inv[8];
  #pragma unroll
  for (int h = 0; h < 8; ++h) inv[h] = 1.f / (s8[h] + 1e-16f);

  if (half == 0) {
    #pragma unroll
    for (int h = 0; h < 8; ++h) {
      uint4 ov;
      ov.x = pack2(acc[h][0] * inv[h], acc[h][1] * inv[h]);
      ov.y = pack2(acc[h][2] * inv[h], acc[h][3] * inv[h]);
      ov.z = pack2(acc[h][4] * inv[h], acc[h][5] * inv[h]);
      ov.w = pack2(acc[h][6] * inv[h], acc[h][7] * inv[h]);
      *(uint4*)(u + (size_t)d * 2048 + h * 256 + cl) = ov;
    }
  }
  if (lane == 0) {
    float pn[8];
    #pragma unroll
    for (int h = 0; h < 8; ++h) pn[h] = p8[h] * inv[h];
    ((float4*)(pp + (size_t)d * 8))[0] = make_float4(pn[0], pn[1], pn[2], pn[3]);
    ((float4*)(pp + (size_t)d * 8))[1] = make_float4(pn[4], pn[5], pn[6], pn[7]);
  }
}

// ---------------- pooled reduction ----------------
__global__ __launch_bounds__(256) void reduce_pp_kernel(const float* __restrict__ pp,
                                                        float* __restrict__ pooled) {
  int tid = threadIdx.x;
  float loc[8] = {0, 0, 0, 0, 0, 0, 0, 0};
  for (int r = blockIdx.x * 256 + tid; r < 20000; r += 80 * 256) {
    float t[8];
    ld8(pp + (size_t)r * 8, t);
    #pragma unroll
    for (int h = 0; h < 8; ++h) loc[h] += t[h];
  }
  #pragma unroll
  for (int off = 1; off < 64; off <<= 1)
    #pragma unroll
    for (int h = 0; h < 8; ++h) loc[h] += __shfl_xor(loc[h], off);
  __shared__ float sred[4][8];
  int wave = tid >> 6, lane = tid & 63;
  if (lane == 0) {
    #pragma unroll
    for (int h = 0; h < 8; ++h) sred[wave][h] = loc[h];
  }
  __syncthreads();
  if (tid < 8) {
    atomicAdd(&pooled[tid], sred[0][tid] + sred[1][tid] + sred[2][tid] + sred[3][tid]);
  }
}

// ---------------- head softmax weights + fused bias ----------------
__global__ __launch_bounds__(256) void headwfb_kernel(const float* __restrict__ pooled,
    const float* __restrict__ b_gat, const float* __restrict__ conv_w,
    const float* __restrict__ conv_b, float* __restrict__ wsoft,
    float* __restrict__ fb) {
  __shared__ float sb[8];
  __shared__ float sw[8];
  int t = threadIdx.x;
  float v = 0.f;
  #pragma unroll
  for (int j = 0; j < 8; ++j) v += b_gat[t * 8 + j];
  #pragma unroll
  for (int off = 1; off < 32; off <<= 1) v += __shfl_xor(v, off);
  if ((t & 31) == 0) sb[t >> 5] = v;
  __syncthreads();
  if (t == 0) {
    const float invNC = 1.0f / (20000.0f * 256.0f);
    float g[8];
    float mx = -1e30f;
    #pragma unroll
    for (int h = 0; h < 8; ++h) {
      float pm = (pooled[h] + 20000.0f * sb[h]) * invNC;
      float gv = pm * conv_w[0] + conv_b[0];
      gv = fmaxf(gv, 0.f);
      g[h] = gv;
      mx = fmaxf(mx, gv);
    }
    float ssum = 0.f;
    #pragma unroll
    for (int h = 0; h < 8; ++h) { g[h] = __expf(g[h] - mx); ssum += g[h]; }
    #pragma unroll
    for (int h = 0; h < 8; ++h) {
      float w = g[h] / ssum;
      wsoft[h] = w;
      sw[h] = w;
    }
  }
  __syncthreads();
  float a = 0.f;
  #pragma unroll
  for (int h = 0; h < 8; ++h) a += sw[h] * b_gat[h * 256 + t];
  fb[t] = a;
}

// wmixT[c][h*256+k] = bf16(wsoft[h] * W_gat[k][h*256+c])
__global__ void wmix_kernel(const float* __restrict__ W, const float* __restrict__ wsoft,
                            short* __restrict__ out) {
  __shared__ float tile[32][33];
  int tx = threadIdx.x, ty = threadIdx.y;
  int h = blockIdx.z;
  float wh = wsoft[h];
  int c0 = blockIdx.x * 32, k0 = blockIdx.y * 32;
  #pragma unroll
  for (int j = ty; j < 32; j += 8)
    tile[j][tx] = W[(size_t)(k0 + j) * 2048 + h * 256 + c0 + tx];
  __syncthreads();
  #pragma unroll
  for (int j = ty; j < 32; j += 8)
    out[(size_t)(c0 + j) * 2048 + h * 256 + k0 + tx] = (short)f2bfu(wh * tile[tx][j]);
}

extern "C" void kernel_launch(void* const* d_in, const int* in_sizes, int n_in,
                              void* d_out, int out_size, void* d_ws, size_t ws_size,
                              hipStream_t stream) {
  (void)in_sizes; (void)n_in; (void)out_size; (void)ws_size;
  const float* x      = (const float*)d_in[0];
  const int*   ei     = (const int*)d_in[1];
  const float* W_gat  = (const float*)d_in[2];
  const float* att_s  = (const float*)d_in[3];
  const float* att_d  = (const float*)d_in[4];
  const float* b_gat  = (const float*)d_in[5];
  const float* conv_w = (const float*)d_in[6];
  const float* conv_b = (const float*)d_in[7];
  const float* W_lin  = (const float*)d_in[8];
  const float* b_lin  = (const float*)d_in[9];
  float* out = (float*)d_out;

  char* p = (char*)d_ws;
  size_t off = 0;
  auto alloc = [&](size_t bytes) -> void* {
    void* r = p + off;
    off = (off + bytes + 255) & ~(size_t)255;
    return r;
  };
  short* x_bf   = (short*)alloc((size_t)20000 * 256 * 2);  // reused as Hf
  short* wmixT  = (short*)alloc((size_t)256 * 2048 * 2);
  short* wlT    = (short*)alloc((size_t)256 * 256 * 2);
  float* ws_s   = (float*)alloc(2048 * 4);
  float* ws_d   = (float*)alloc(2048 * 4);
  float* ws_r   = (float*)alloc(2048 * 4);
  float* a_s    = (float*)alloc((size_t)20000 * 8 * 4);
  float* a_d    = (float*)alloc((size_t)20000 * 8 * 4);
  float* rs     = (float*)alloc((size_t)20000 * 8 * 4);
  int*   deg    = (int*)alloc(20000 * 4);
  float* pooled = (float*)alloc(8 * 4);
  float* wsoft  = (float*)alloc(8 * 4);
  float* fb     = (float*)alloc(256 * 4);
  int*   rowptr = (int*)alloc(20001 * 4);
  int*   cursor = (int*)alloc(20000 * 4);
  int*   csr    = (int*)alloc(200000 * 4);
  float* pp     = (float*)alloc((size_t)20000 * 8 * 4);
  short* u      = (short*)alloc((size_t)20000 * 2048 * 2);
  short* Hf     = x_bf;  // x_bf dead after alphaz

  hipMemsetAsync(deg, 0, 20000 * 4, stream);
  hipMemsetAsync(pooled, 0, 8 * 4, stream);

  prep1_kernel<<<878, 256, 0, stream>>>(W_lin, wlT, W_gat, att_s, att_d,
                                        ws_s, ws_d, ws_r, ei, deg);
  scan_kernel<<<1, 1024, 0, stream>>>(deg, rowptr, cursor, 20000);
  asd_kernel<<<625, 256, 0, stream>>>(x, ws_s, ws_d, ws_r, a_s, a_d, rs, x_bf);
  scatter_kernel<<<782, 256, 0, stream>>>(ei, cursor, csr, 200000);
  alphaz_kernel<<<5000, 256, 0, stream>>>(x_bf, a_s, a_d, rs, rowptr, csr, u, pp);
  reduce_pp_kernel<<<80, 256, 0, stream>>>(pp, pooled);
  headwfb_kernel<<<1, 256, 0, stream>>>(pooled, b_gat, conv_w, conv_b, wsoft, fb);
  wmix_kernel<<<dim3(8, 8, 8), dim3(32, 8), 0, stream>>>(W_gat, wsoft, wmixT);
  gemm_fused_kernel<<<313, 256, 0, stream>>>(u, wmixT, wlT, Hf, out, fb, x, b_lin, 20000);
}

// Round 14
// 194.369 us; speedup vs baseline: 1.0711x; 1.0711x over previous
//
#include <hip/hip_runtime.h>
#include <hip/hip_bf16.h>

// N=20000 nodes, E=200000 edges, H=8, C=256, IN=256, OUT=250, H*C=2048.
// R14: alphaz = 1 wave/dst, 8 heads x 4ch/lane (small state: acc[8][4]);
//      pooled partial computed in EPILOGUE from acc & ws_r (rs deleted
//      everywhere -> fewer VGPRs + less asd work); R13 gemm fusion kept.

typedef __attribute__((ext_vector_type(8))) short short8v;
typedef __attribute__((ext_vector_type(4))) float float4v;

__device__ __forceinline__ unsigned f2bfu(float f) {
  unsigned u = __float_as_uint(f);
  return (u + 0x7fffu + ((u >> 16) & 1u)) >> 16;  // RNE f32 -> bf16
}
__device__ __forceinline__ float bfu_lo(unsigned u) { return __uint_as_float(u << 16); }
__device__ __forceinline__ float bfu_hi(unsigned u) { return __uint_as_float(u & 0xffff0000u); }
__device__ __forceinline__ unsigned pack2(float a, float b) { return f2bfu(a) | (f2bfu(b) << 16); }

__device__ __forceinline__ void ld8(const float* p, float* v) {
  float4 a = ((const float4*)p)[0], b = ((const float4*)p)[1];
  v[0] = a.x; v[1] = a.y; v[2] = a.z; v[3] = a.w;
  v[4] = b.x; v[5] = b.y; v[6] = b.z; v[7] = b.w;
}

__device__ __forceinline__ float bcast(float x, int e) {
  return __uint_as_float((unsigned)__builtin_amdgcn_readlane((int)__float_as_uint(x), e));
}

__device__ __forceinline__ void gll16(const void* g, void* l) {
  __builtin_amdgcn_global_load_lds(
      (__attribute__((address_space(1))) void*)const_cast<void*>(g),
      (__attribute__((address_space(3))) void*)(l), 16, 0, 0);
}

// ---------------- prep1: transpose(W_lin) + prepws + hist ----------------
__global__ __launch_bounds__(256) void prep1_kernel(
    const float* __restrict__ W_lin, short* __restrict__ wlT,
    const float* __restrict__ W, const float* __restrict__ att_s,
    const float* __restrict__ att_d, float* __restrict__ ws_s,
    float* __restrict__ ws_d, float* __restrict__ ws_r,
    const int* __restrict__ ei, int* __restrict__ deg) {
  __shared__ float smem[4096];
  int b = blockIdx.x;
  int t = threadIdx.x;
  if (b < 64) {
    float (*tile)[33] = (float(*)[33])smem;
    int tx = t & 31, ty = t >> 5;
    int c0 = (b & 7) * 32, r0 = (b >> 3) * 32;
    #pragma unroll
    for (int j = ty; j < 32; j += 8) {
      int r = r0 + j, c = c0 + tx;
      tile[j][tx] = (c < 250) ? W_lin[(size_t)r * 250 + c] : 0.f;
    }
    __syncthreads();
    #pragma unroll
    for (int j = ty; j < 32; j += 8) {
      int c = c0 + j, r = r0 + tx;
      wlT[(size_t)c * 256 + r] = (short)f2bfu(tile[tx][j]);
    }
  } else if (b < 96) {
    float* sas = smem;
    float* sad = smem + 2048;
    for (int i = t; i < 2048; i += 256) { sas[i] = att_s[i]; sad[i] = att_d[i]; }
    __syncthreads();
    int kk = t >> 5, h = (t >> 2) & 7, q = t & 3;
    int k = (b - 64) * 8 + kk;
    const float4* wr = (const float4*)(W + (size_t)k * 2048 + h * 256 + q * 64);
    const float* as = sas + h * 256 + q * 64;
    const float* ad = sad + h * 256 + q * 64;
    float s = 0.f, dd = 0.f, r = 0.f;
    #pragma unroll
    for (int c4 = 0; c4 < 16; ++c4) {
      float4 wv = wr[c4];
      int c = c4 * 4;
      s  += wv.x * as[c] + wv.y * as[c + 1] + wv.z * as[c + 2] + wv.w * as[c + 3];
      dd += wv.x * ad[c] + wv.y * ad[c + 1] + wv.z * ad[c + 2] + wv.w * ad[c + 3];
      r  += wv.x + wv.y + wv.z + wv.w;
    }
    #pragma unroll
    for (int off = 1; off < 4; off <<= 1) {
      s += __shfl_xor(s, off);
      dd += __shfl_xor(dd, off);
      r += __shfl_xor(r, off);
    }
    if (q == 0) {
      int g = k * 8 + h;
      ws_s[g] = s;
      ws_d[g] = dd;
      ws_r[g] = r;
    }
  } else {
    int e = (b - 96) * 256 + t;
    if (e < 200000) atomicAdd(&deg[ei[200000 + e]], 1);
  }
}

// a_s/a_d + coalesced x_bf (thread (node,h) owns chunks 8h..8h+7)
__global__ __launch_bounds__(256) void asd_kernel(const float* __restrict__ x,
    const float* __restrict__ ws_s, const float* __restrict__ ws_d,
    float* __restrict__ a_s, float* __restrict__ a_d, short* __restrict__ x_bf) {
  __shared__ float ls[2048], ld2[2048];
  int tid = threadIdx.x;
  for (int i = tid; i < 2048; i += 256) { ls[i] = ws_s[i]; ld2[i] = ws_d[i]; }
  __syncthreads();
  int node = blockIdx.x * 32 + (tid >> 3);
  int h = tid & 7;
  const float4* xr = (const float4*)(x + (size_t)node * 256);
  float as = 0.f, ad = 0.f;
  #pragma unroll 1
  for (int g = 0; g < 8; ++g) {
    bool own = (g == h);
    int bufi[16];
    #pragma unroll
    for (int j = 0; j < 8; ++j) {
      int k4 = g * 8 + j;
      float4 v = xr[k4];
      int k8 = k4 * 32 + h;
      as += v.x * ls[k8] + v.y * ls[k8 + 8] + v.z * ls[k8 + 16] + v.w * ls[k8 + 24];
      ad += v.x * ld2[k8] + v.y * ld2[k8 + 8] + v.z * ld2[k8 + 16] + v.w * ld2[k8 + 24];
      bufi[2 * j] = (int)pack2(v.x, v.y);
      bufi[2 * j + 1] = (int)pack2(v.z, v.w);
    }
    if (own) {
      int4* dst = (int4*)(x_bf + (size_t)node * 256 + h * 32);
      dst[0] = make_int4(bufi[0], bufi[1], bufi[2], bufi[3]);
      dst[1] = make_int4(bufi[4], bufi[5], bufi[6], bufi[7]);
      dst[2] = make_int4(bufi[8], bufi[9], bufi[10], bufi[11]);
      dst[3] = make_int4(bufi[12], bufi[13], bufi[14], bufi[15]);
    }
  }
  a_s[node * 8 + h] = as;
  a_d[node * 8 + h] = ad;
}

// ---------------- fused double GEMM ----------------
// Stage 1: Hf = relu(u @ wmixT^T + fb + x)   [M x 256] bf16  (K=2048)
// Stage 2: out = Hf @ wlT^T + b_lin          [M x 250] f32   (K=256, L2-hot A)
__global__ __launch_bounds__(256, 2) void gemm_fused_kernel(
    const short* __restrict__ u, const short* __restrict__ wmixT,
    const short* __restrict__ wlT, short* __restrict__ Hf,
    float* __restrict__ out, const float* __restrict__ fb,
    const float* __restrict__ x, const float* __restrict__ b_lin, int M) {
  __shared__ short lA[64 * 128];    // 16 KB
  __shared__ short lB[256 * 128];   // 64 KB
  int tid = threadIdx.x;
  int wave = tid >> 6, lane = tid & 63;
  int m0 = blockIdx.x << 6;
  int lr = lane & 15, lq = lane >> 4;
  int lrow4 = lane >> 4;
  int pch = lane & 15;

  float4v acc[4][4];
  #pragma unroll
  for (int i = 0; i < 4; ++i)
    #pragma unroll
    for (int j = 0; j < 4; ++j) acc[i][j] = (float4v){0.f, 0.f, 0.f, 0.f};

  int rowlA[4], growA[4], logA[4];
  #pragma unroll
  for (int it = 0; it < 4; ++it) {
    rowlA[it] = wave * 16 + it * 4 + lrow4;
    int grow = m0 + rowlA[it];
    if (grow >= M) grow = M - 1;
    growA[it] = grow;
    logA[it] = pch ^ (rowlA[it] & 7);
  }
  int rowB[16], logB[16];
  #pragma unroll
  for (int it = 0; it < 16; ++it) {
    rowB[it] = wave * 64 + it * 4 + lrow4;
    logB[it] = pch ^ (rowB[it] & 7);
  }

  // ---- stage 1: K=2048 ----
  for (int t = 0; t < 16; ++t) {
    int k0 = t << 7;
    __syncthreads();
    #pragma unroll
    for (int it = 0; it < 4; ++it)
      gll16(u + (size_t)growA[it] * 2048 + logA[it] * 8 + k0, lA + (wave * 16 + it * 4) * 128);
    #pragma unroll
    for (int it = 0; it < 16; ++it)
      gll16(wmixT + (size_t)rowB[it] * 2048 + logB[it] * 8 + k0, lB + (wave * 64 + it * 4) * 128);
    __syncthreads();
    #pragma unroll
    for (int ks = 0; ks < 4; ++ks) {
      int phys = ((ks * 4 + lq) ^ (lr & 7)) * 8;
      short8v af[4], bfv[4];
      #pragma unroll
      for (int i = 0; i < 4; ++i)
        af[i] = *(const short8v*)(lA + (i * 16 + lr) * 128 + phys);
      #pragma unroll
      for (int j = 0; j < 4; ++j)
        bfv[j] = *(const short8v*)(lB + (wave * 64 + j * 16 + lr) * 128 + phys);
      #pragma unroll
      for (int i = 0; i < 4; ++i)
        #pragma unroll
        for (int j = 0; j < 4; ++j)
          acc[i][j] = __builtin_amdgcn_mfma_f32_16x16x32_bf16(af[i], bfv[j], acc[i][j], 0, 0, 0);
    }
  }
  #pragma unroll
  for (int i = 0; i < 4; ++i) {
    #pragma unroll
    for (int jj = 0; jj < 4; ++jj) {
      int row = m0 + i * 16 + lq * 4 + jj;
      if (row >= M) continue;
      #pragma unroll
      for (int j = 0; j < 4; ++j) {
        int col = wave * 64 + j * 16 + lr;
        float o = acc[i][j][jj] + fb[col] + x[(size_t)row * 256 + col];
        Hf[(size_t)row * 256 + col] = (short)f2bfu(fmaxf(o, 0.f));
      }
    }
  }

  // ---- stage 2: out = Hf @ wlT^T + b_lin, K=256 ----
  #pragma unroll
  for (int i = 0; i < 4; ++i)
    #pragma unroll
    for (int j = 0; j < 4; ++j) acc[i][j] = (float4v){0.f, 0.f, 0.f, 0.f};

  for (int t = 0; t < 2; ++t) {
    int k0 = t << 7;
    __syncthreads();   // drains vmcnt: stage-1 stores visible; LDS safe to overwrite
    #pragma unroll
    for (int it = 0; it < 4; ++it)
      gll16(Hf + (size_t)growA[it] * 256 + logA[it] * 8 + k0, lA + (wave * 16 + it * 4) * 128);
    #pragma unroll
    for (int it = 0; it < 16; ++it)
      gll16(wlT + (size_t)rowB[it] * 256 + logB[it] * 8 + k0, lB + (wave * 64 + it * 4) * 128);
    __syncthreads();
    #pragma unroll
    for (int ks = 0; ks < 4; ++ks) {
      int phys = ((ks * 4 + lq) ^ (lr & 7)) * 8;
      short8v af[4], bfv[4];
      #pragma unroll
      for (int i = 0; i < 4; ++i)
        af[i] = *(const short8v*)(lA + (i * 16 + lr) * 128 + phys);
      #pragma unroll
      for (int j = 0; j < 4; ++j)
        bfv[j] = *(const short8v*)(lB + (wave * 64 + j * 16 + lr) * 128 + phys);
      #pragma unroll
      for (int i = 0; i < 4; ++i)
        #pragma unroll
        for (int j = 0; j < 4; ++j)
          acc[i][j] = __builtin_amdgcn_mfma_f32_16x16x32_bf16(af[i], bfv[j], acc[i][j], 0, 0, 0);
    }
  }
  #pragma unroll
  for (int i = 0; i < 4; ++i) {
    #pragma unroll
    for (int jj = 0; jj < 4; ++jj) {
      int row = m0 + i * 16 + lq * 4 + jj;
      if (row >= M) continue;
      #pragma unroll
      for (int j = 0; j < 4; ++j) {
        int col = wave * 64 + j * 16 + lr;
        if (col < 250) out[(size_t)row * 250 + col] = acc[i][j][jj] + b_lin[col];
      }
    }
  }
}

// ---------------- CSR scan / scatter ----------------

__global__ __launch_bounds__(1024) void scan_kernel(const int* __restrict__ deg,
                                                    int* __restrict__ rowptr,
                                                    int* __restrict__ cursor, int n) {
  __shared__ int part[1024];
  int t = threadIdx.x;
  int base = t * 20;
  int loc[20];
  int run = 0;
  #pragma unroll
  for (int j = 0; j < 20; ++j) {
    int idx = base + j;
    int v = (idx < n) ? deg[idx] : 0;
    loc[j] = run;
    run += v;
  }
  part[t] = run;
  __syncthreads();
  for (int off = 1; off < 1024; off <<= 1) {
    int add = (t >= off) ? part[t - off] : 0;
    __syncthreads();
    part[t] += add;
    __syncthreads();
  }
  int off0 = (t > 0) ? part[t - 1] : 0;
  #pragma unroll
  for (int j = 0; j < 20; ++j) {
    int idx = base + j;
    if (idx < n) {
      int v = off0 + loc[j];
      rowptr[idx] = v;
      cursor[idx] = v;
    }
  }
  if (t == 1023) rowptr[n] = part[1023];
}

__global__ void scatter_kernel(const int* __restrict__ ei, int* __restrict__ cursor,
                               int* __restrict__ csr_src, int E) {
  int e = blockIdx.x * 256 + threadIdx.x;
  if (e < E) {
    int pos = atomicAdd(&cursor[ei[E + e]], 1);
    csr_src[pos] = ei[e];
  }
}

// ---------------- fused softmax + z-aggregate (1 wave/dst, 8 heads, 4ch/lane) ----
// No-max softmax, deferred normalization. Self edge = edge #deg (src=d).
// u[d][h*256+c] = (1/s_h) sum_e ex_eh x_bf[src_e][c]
// pp[d][h]      = sum_k z[d][h][k] * ws_r[k*8+h]  (epilogue; == sum_c agg_nobias)
__global__ __launch_bounds__(256) void alphaz_kernel(
    const short* __restrict__ x_bf, const float* __restrict__ a_s,
    const float* __restrict__ a_d, const float* __restrict__ ws_r,
    const int* __restrict__ rowptr, const int* __restrict__ csr,
    short* __restrict__ u, float* __restrict__ pp) {
  int d = blockIdx.x * 4 + (threadIdx.x >> 6);
  int lane = threadIdx.x & 63;
  int cl = lane * 4;              // 4 channels per lane
  int beg = rowptr[d];
  int deg = rowptr[d + 1] - beg;
  int nb = deg + 1;               // + self at index deg

  float ad8[8];
  ld8(a_d + (size_t)d * 8, ad8);

  float acc[8][4];
  #pragma unroll
  for (int h = 0; h < 8; ++h)
    #pragma unroll
    for (int c = 0; c < 4; ++c) acc[h][c] = 0.f;
  float s8[8] = {0, 0, 0, 0, 0, 0, 0, 0};

  for (int base = 0; base < nb; base += 64) {
    int i = base + lane;
    bool act = i < nb;
    int srcv = d;                 // self (i==deg) and inactive default
    if (i < deg) srcv = csr[beg + i];
    float ex[8];
    {
      float t8[8];
      ld8(a_s + (size_t)srcv * 8, t8);
      #pragma unroll
      for (int h = 0; h < 8; ++h) {
        float e = t8[h] + ad8[h];
        e = (e > 0.f) ? e : 0.2f * e;
        float xx = act ? __expf(e) : 0.f;
        ex[h] = xx;
        s8[h] += xx;
      }
    }
    int cnt = nb - base;
    if (cnt > 64) cnt = 64;
    for (int e = 0; e < cnt; ++e) {
      int sb = __builtin_amdgcn_readlane(srcv, e);
      uint2 v = *(const uint2*)(x_bf + (size_t)sb * 256 + cl);
      float q[8];
      #pragma unroll
      for (int h = 0; h < 8; ++h) q[h] = bcast(ex[h], e);
      float xv0 = bfu_lo(v.x), xv1 = bfu_hi(v.x);
      float xv2 = bfu_lo(v.y), xv3 = bfu_hi(v.y);
      #pragma unroll
      for (int h = 0; h < 8; ++h) {
        acc[h][0] += q[h] * xv0;
        acc[h][1] += q[h] * xv1;
        acc[h][2] += q[h] * xv2;
        acc[h][3] += q[h] * xv3;
      }
    }
  }

  // s reduce across lanes
  #pragma unroll
  for (int off = 1; off < 64; off <<= 1)
    #pragma unroll
    for (int h = 0; h < 8; ++h) s8[h] += __shfl_xor(s8[h], off);
  float inv[8];
  #pragma unroll
  for (int h = 0; h < 8; ++h) inv[h] = 1.f / (s8[h] + 1e-16f);

  // write u (normalized, bf16)
  #pragma unroll
  for (int h = 0; h < 8; ++h) {
    uint2 ov;
    ov.x = pack2(acc[h][0] * inv[h], acc[h][1] * inv[h]);
    ov.y = pack2(acc[h][2] * inv[h], acc[h][3] * inv[h]);
    *(uint2*)(u + (size_t)d * 2048 + h * 256 + cl) = ov;
  }

  // pooled partial: pp[d][h] = sum_k z*ws_r; lane holds k = cl..cl+3 for all h
  float ppl[8] = {0, 0, 0, 0, 0, 0, 0, 0};
  {
    const float4* wr = (const float4*)(ws_r + (size_t)cl * 8);  // 32 floats
    #pragma unroll
    for (int c = 0; c < 4; ++c) {
      float4 wa = wr[c * 2], wb = wr[c * 2 + 1];  // ws_r[(cl+c)*8 + 0..7]
      float zc[8];
      #pragma unroll
      for (int h = 0; h < 8; ++h) zc[h] = acc[h][c] * inv[h];
      ppl[0] += zc[0] * wa.x; ppl[1] += zc[1] * wa.y;
      ppl[2] += zc[2] * wa.z; ppl[3] += zc[3] * wa.w;
      ppl[4] += zc[4] * wb.x; ppl[5] += zc[5] * wb.y;
      ppl[6] += zc[6] * wb.z; ppl[7] += zc[7] * wb.w;
    }
  }
  #pragma unroll
  for (int off = 1; off < 64; off <<= 1)
    #pragma unroll
    for (int h = 0; h < 8; ++h) ppl[h] += __shfl_xor(ppl[h], off);
  if (lane == 0) {
    ((float4*)(pp + (size_t)d * 8))[0] = make_float4(ppl[0], ppl[1], ppl[2], ppl[3]);
    ((float4*)(pp + (size_t)d * 8))[1] = make_float4(ppl[4], ppl[5], ppl[6], ppl[7]);
  }
}

// ---------------- pooled reduction ----------------
__global__ __launch_bounds__(256) void reduce_pp_kernel(const float* __restrict__ pp,
                                                        float* __restrict__ pooled) {
  int tid = threadIdx.x;
  float loc[8] = {0, 0, 0, 0, 0, 0, 0, 0};
  for (int r = blockIdx.x * 256 + tid; r < 20000; r += 80 * 256) {
    float t[8];
    ld8(pp + (size_t)r * 8, t);
    #pragma unroll
    for (int h = 0; h < 8; ++h) loc[h] += t[h];
  }
  #pragma unroll
  for (int off = 1; off < 64; off <<= 1)
    #pragma unroll
    for (int h = 0; h < 8; ++h) loc[h] += __shfl_xor(loc[h], off);
  __shared__ float sred[4][8];
  int wave = tid >> 6, lane = tid & 63;
  if (lane == 0) {
    #pragma unroll
    for (int h = 0; h < 8; ++h) sred[wave][h] = loc[h];
  }
  __syncthreads();
  if (tid < 8) {
    atomicAdd(&pooled[tid], sred[0][tid] + sred[1][tid] + sred[2][tid] + sred[3][tid]);
  }
}

// ---------------- head softmax weights + fused bias ----------------
__global__ __launch_bounds__(256) void headwfb_kernel(const float* __restrict__ pooled,
    const float* __restrict__ b_gat, const float* __restrict__ conv_w,
    const float* __restrict__ conv_b, float* __restrict__ wsoft,
    float* __restrict__ fb) {
  __shared__ float sb[8];
  __shared__ float sw[8];
  int t = threadIdx.x;
  float v = 0.f;
  #pragma unroll
  for (int j = 0; j < 8; ++j) v += b_gat[t * 8 + j];
  #pragma unroll
  for (int off = 1; off < 32; off <<= 1) v += __shfl_xor(v, off);
  if ((t & 31) == 0) sb[t >> 5] = v;
  __syncthreads();
  if (t == 0) {
    const float invNC = 1.0f / (20000.0f * 256.0f);
    float g[8];
    float mx = -1e30f;
    #pragma unroll
    for (int h = 0; h < 8; ++h) {
      float pm = (pooled[h] + 20000.0f * sb[h]) * invNC;
      float gv = pm * conv_w[0] + conv_b[0];
      gv = fmaxf(gv, 0.f);
      g[h] = gv;
      mx = fmaxf(mx, gv);
    }
    float ssum = 0.f;
    #pragma unroll
    for (int h = 0; h < 8; ++h) { g[h] = __expf(g[h] - mx); ssum += g[h]; }
    #pragma unroll
    for (int h = 0; h < 8; ++h) {
      float w = g[h] / ssum;
      wsoft[h] = w;
      sw[h] = w;
    }
  }
  __syncthreads();
  float a = 0.f;
  #pragma unroll
  for (int h = 0; h < 8; ++h) a += sw[h] * b_gat[h * 256 + t];
  fb[t] = a;
}

// wmixT[c][h*256+k] = bf16(wsoft[h] * W_gat[k][h*256+c])
__global__ void wmix_kernel(const float* __restrict__ W, const float* __restrict__ wsoft,
                            short* __restrict__ out) {
  __shared__ float tile[32][33];
  int tx = threadIdx.x, ty = threadIdx.y;
  int h = blockIdx.z;
  float wh = wsoft[h];
  int c0 = blockIdx.x * 32, k0 = blockIdx.y * 32;
  #pragma unroll
  for (int j = ty; j < 32; j += 8)
    tile[j][tx] = W[(size_t)(k0 + j) * 2048 + h * 256 + c0 + tx];
  __syncthreads();
  #pragma unroll
  for (int j = ty; j < 32; j += 8)
    out[(size_t)(c0 + j) * 2048 + h * 256 + k0 + tx] = (short)f2bfu(wh * tile[tx][j]);
}

extern "C" void kernel_launch(void* const* d_in, const int* in_sizes, int n_in,
                              void* d_out, int out_size, void* d_ws, size_t ws_size,
                              hipStream_t stream) {
  (void)in_sizes; (void)n_in; (void)out_size; (void)ws_size;
  const float* x      = (const float*)d_in[0];
  const int*   ei     = (const int*)d_in[1];
  const float* W_gat  = (const float*)d_in[2];
  const float* att_s  = (const float*)d_in[3];
  const float* att_d  = (const float*)d_in[4];
  const float* b_gat  = (const float*)d_in[5];
  const float* conv_w = (const float*)d_in[6];
  const float* conv_b = (const float*)d_in[7];
  const float* W_lin  = (const float*)d_in[8];
  const float* b_lin  = (const float*)d_in[9];
  float* out = (float*)d_out;

  char* p = (char*)d_ws;
  size_t off = 0;
  auto alloc = [&](size_t bytes) -> void* {
    void* r = p + off;
    off = (off + bytes + 255) & ~(size_t)255;
    return r;
  };
  short* x_bf   = (short*)alloc((size_t)20000 * 256 * 2);  // reused as Hf
  short* wmixT  = (short*)alloc((size_t)256 * 2048 * 2);
  short* wlT    = (short*)alloc((size_t)256 * 256 * 2);
  float* ws_s   = (float*)alloc(2048 * 4);
  float* ws_d   = (float*)alloc(2048 * 4);
  float* ws_r   = (float*)alloc(2048 * 4);
  float* a_s    = (float*)alloc((size_t)20000 * 8 * 4);
  float* a_d    = (float*)alloc((size_t)20000 * 8 * 4);
  int*   deg    = (int*)alloc(20000 * 4);
  float* pooled = (float*)alloc(8 * 4);
  float* wsoft  = (float*)alloc(8 * 4);
  float* fb     = (float*)alloc(256 * 4);
  int*   rowptr = (int*)alloc(20001 * 4);
  int*   cursor = (int*)alloc(20000 * 4);
  int*   csr    = (int*)alloc(200000 * 4);
  float* pp     = (float*)alloc((size_t)20000 * 8 * 4);
  short* u      = (short*)alloc((size_t)20000 * 2048 * 2);
  short* Hf     = x_bf;  // x_bf dead after alphaz

  hipMemsetAsync(deg, 0, 20000 * 4, stream);
  hipMemsetAsync(pooled, 0, 8 * 4, stream);

  prep1_kernel<<<878, 256, 0, stream>>>(W_lin, wlT, W_gat, att_s, att_d,
                                        ws_s, ws_d, ws_r, ei, deg);
  scan_kernel<<<1, 1024, 0, stream>>>(deg, rowptr, cursor, 20000);
  asd_kernel<<<625, 256, 0, stream>>>(x, ws_s, ws_d, a_s, a_d, x_bf);
  scatter_kernel<<<782, 256, 0, stream>>>(ei, cursor, csr, 200000);
  alphaz_kernel<<<5000, 256, 0, stream>>>(x_bf, a_s, a_d, ws_r, rowptr, csr, u, pp);
  reduce_pp_kernel<<<80, 256, 0, stream>>>(pp, pooled);
  headwfb_kernel<<<1, 256, 0, stream>>>(pooled, b_gat, conv_w, conv_b, wsoft, fb);
  wmix_kernel<<<dim3(8, 8, 8), dim3(32, 8), 0, stream>>>(W_gat, wsoft, wmixT);
  gemm_fused_kernel<<<313, 256, 0, stream>>>(u, wmixT, wlT, Hf, out, fb, x, b_lin, 20000);
}

// Round 15
// 186.322 us; speedup vs baseline: 1.1173x; 1.0432x over previous
//
#include <hip/hip_runtime.h>
#include <hip/hip_bf16.h>

// N=20000 nodes, E=200000 edges, H=8, C=256, IN=256, OUT=250, H*C=2048.
// R15: un-fuse GEMMs; 64x64 tiles (R4 occupancy) + XCD-aware bijective block
//      map (all 4 n-tiles of an m-tile on one XCD -> A fetched once, T1) +
//      R5's measured-conflict-free BK=32 swizzle. alphaz/asd/etc unchanged.

typedef __attribute__((ext_vector_type(8))) short short8v;
typedef __attribute__((ext_vector_type(4))) float float4v;

__device__ __forceinline__ unsigned f2bfu(float f) {
  unsigned u = __float_as_uint(f);
  return (u + 0x7fffu + ((u >> 16) & 1u)) >> 16;  // RNE f32 -> bf16
}
__device__ __forceinline__ float bfu_lo(unsigned u) { return __uint_as_float(u << 16); }
__device__ __forceinline__ float bfu_hi(unsigned u) { return __uint_as_float(u & 0xffff0000u); }
__device__ __forceinline__ unsigned pack2(float a, float b) { return f2bfu(a) | (f2bfu(b) << 16); }

__device__ __forceinline__ void ld8(const float* p, float* v) {
  float4 a = ((const float4*)p)[0], b = ((const float4*)p)[1];
  v[0] = a.x; v[1] = a.y; v[2] = a.z; v[3] = a.w;
  v[4] = b.x; v[5] = b.y; v[6] = b.z; v[7] = b.w;
}

__device__ __forceinline__ float bcast(float x, int e) {
  return __uint_as_float((unsigned)__builtin_amdgcn_readlane((int)__float_as_uint(x), e));
}

__device__ __forceinline__ void gll16(const void* g, void* l) {
  __builtin_amdgcn_global_load_lds(
      (__attribute__((address_space(1))) void*)const_cast<void*>(g),
      (__attribute__((address_space(3))) void*)(l), 16, 0, 0);
}

// ---------------- prep1: transpose(W_lin) + prepws + hist ----------------
__global__ __launch_bounds__(256) void prep1_kernel(
    const float* __restrict__ W_lin, short* __restrict__ wlT,
    const float* __restrict__ W, const float* __restrict__ att_s,
    const float* __restrict__ att_d, float* __restrict__ ws_s,
    float* __restrict__ ws_d, float* __restrict__ ws_r,
    const int* __restrict__ ei, int* __restrict__ deg) {
  __shared__ float smem[4096];
  int b = blockIdx.x;
  int t = threadIdx.x;
  if (b < 64) {
    float (*tile)[33] = (float(*)[33])smem;
    int tx = t & 31, ty = t >> 5;
    int c0 = (b & 7) * 32, r0 = (b >> 3) * 32;
    #pragma unroll
    for (int j = ty; j < 32; j += 8) {
      int r = r0 + j, c = c0 + tx;
      tile[j][tx] = (c < 250) ? W_lin[(size_t)r * 250 + c] : 0.f;
    }
    __syncthreads();
    #pragma unroll
    for (int j = ty; j < 32; j += 8) {
      int c = c0 + j, r = r0 + tx;
      wlT[(size_t)c * 256 + r] = (short)f2bfu(tile[tx][j]);
    }
  } else if (b < 96) {
    float* sas = smem;
    float* sad = smem + 2048;
    for (int i = t; i < 2048; i += 256) { sas[i] = att_s[i]; sad[i] = att_d[i]; }
    __syncthreads();
    int kk = t >> 5, h = (t >> 2) & 7, q = t & 3;
    int k = (b - 64) * 8 + kk;
    const float4* wr = (const float4*)(W + (size_t)k * 2048 + h * 256 + q * 64);
    const float* as = sas + h * 256 + q * 64;
    const float* ad = sad + h * 256 + q * 64;
    float s = 0.f, dd = 0.f, r = 0.f;
    #pragma unroll
    for (int c4 = 0; c4 < 16; ++c4) {
      float4 wv = wr[c4];
      int c = c4 * 4;
      s  += wv.x * as[c] + wv.y * as[c + 1] + wv.z * as[c + 2] + wv.w * as[c + 3];
      dd += wv.x * ad[c] + wv.y * ad[c + 1] + wv.z * ad[c + 2] + wv.w * ad[c + 3];
      r  += wv.x + wv.y + wv.z + wv.w;
    }
    #pragma unroll
    for (int off = 1; off < 4; off <<= 1) {
      s += __shfl_xor(s, off);
      dd += __shfl_xor(dd, off);
      r += __shfl_xor(r, off);
    }
    if (q == 0) {
      int g = k * 8 + h;
      ws_s[g] = s;
      ws_d[g] = dd;
      ws_r[g] = r;
    }
  } else {
    int e = (b - 96) * 256 + t;
    if (e < 200000) atomicAdd(&deg[ei[200000 + e]], 1);
  }
}

// a_s/a_d + coalesced x_bf (thread (node,h) owns chunks 8h..8h+7)
__global__ __launch_bounds__(256) void asd_kernel(const float* __restrict__ x,
    const float* __restrict__ ws_s, const float* __restrict__ ws_d,
    float* __restrict__ a_s, float* __restrict__ a_d, short* __restrict__ x_bf) {
  __shared__ float ls[2048], ld2[2048];
  int tid = threadIdx.x;
  for (int i = tid; i < 2048; i += 256) { ls[i] = ws_s[i]; ld2[i] = ws_d[i]; }
  __syncthreads();
  int node = blockIdx.x * 32 + (tid >> 3);
  int h = tid & 7;
  const float4* xr = (const float4*)(x + (size_t)node * 256);
  float as = 0.f, ad = 0.f;
  #pragma unroll 1
  for (int g = 0; g < 8; ++g) {
    bool own = (g == h);
    int bufi[16];
    #pragma unroll
    for (int j = 0; j < 8; ++j) {
      int k4 = g * 8 + j;
      float4 v = xr[k4];
      int k8 = k4 * 32 + h;
      as += v.x * ls[k8] + v.y * ls[k8 + 8] + v.z * ls[k8 + 16] + v.w * ls[k8 + 24];
      ad += v.x * ld2[k8] + v.y * ld2[k8 + 8] + v.z * ld2[k8 + 16] + v.w * ld2[k8 + 24];
      bufi[2 * j] = (int)pack2(v.x, v.y);
      bufi[2 * j + 1] = (int)pack2(v.z, v.w);
    }
    if (own) {
      int4* dst = (int4*)(x_bf + (size_t)node * 256 + h * 32);
      dst[0] = make_int4(bufi[0], bufi[1], bufi[2], bufi[3]);
      dst[1] = make_int4(bufi[4], bufi[5], bufi[6], bufi[7]);
      dst[2] = make_int4(bufi[8], bufi[9], bufi[10], bufi[11]);
      dst[3] = make_int4(bufi[12], bufi[13], bufi[14], bufi[15]);
    }
  }
  a_s[node * 8 + h] = as;
  a_d[node * 8 + h] = ad;
}

// ---------------- bf16 MFMA GEMM (64x64 tile, BK=32, XCD-mapped grid) ----------------
// Grid = 1280: g -> (i,j) with k=g&7, t=g>>3, i=k+8*(t>>2) [m-tile], j=t&3 [n-tile];
// all 4 j's of one i land on the same XCD (consecutive t, same k) -> A L2-reuse.
// R5-verified conflict-free swizzle: store chunk (lane&3)^((row>>1)&3), read lq^((lr>>1)&3).
// EPI=1: f32 store + bias, col<Nout.  EPI=2: bf16 store of relu(acc+bias+xres).
template <int EPI>
__global__ __launch_bounds__(256, 4) void gemm_kernel(
    const short* __restrict__ A, const short* __restrict__ BT,
    int M, int K,
    short* __restrict__ Cb, float* __restrict__ Cf,
    const float* __restrict__ bias, const float* __restrict__ xres, int Nout) {
  int g = blockIdx.x;
  int xk = g & 7, tt = g >> 3;
  int it = xk + 8 * (tt >> 2);      // m-tile index
  if (it >= ((M + 63) >> 6)) return;
  int m0 = it << 6;
  int n0 = (tt & 3) << 6;

  __shared__ short lA[64 * 32];     // 4 KB
  __shared__ short lB[64 * 32];     // 4 KB
  int tid = threadIdx.x;
  int wave = tid >> 6, lane = tid & 63;
  int wm = wave >> 1, wn = wave & 1;
  int lr = lane & 15, lq = lane >> 4;

  float4v acc[2][2];
  #pragma unroll
  for (int i = 0; i < 2; ++i)
    #pragma unroll
    for (int j = 0; j < 2; ++j) acc[i][j] = (float4v){0.f, 0.f, 0.f, 0.f};

  // staging (R5 scheme): thread stages row wave*16 + (lane>>2), swizzled chunk
  int sr = lane >> 2;               // 0..15
  int sw = (lane >> 3) & 3;         // (row>>1)&3 with row = wave*16+sr
  int sc = ((lane & 3) ^ sw) << 3;  // swizzled k-element offset
  int arow = m0 + wave * 16 + sr;
  if (arow >= M) arow = M - 1;      // clamp; masked at store
  const short* pA = A + (size_t)arow * K + sc;
  const short* pB = BT + (size_t)(n0 + wave * 16 + sr) * K + sc;

  int rsw = ((lr >> 1) & 3) ^ lq;   // read chunk slot

  for (int k0 = 0; k0 < K; k0 += 32) {
    __syncthreads();
    gll16(pA + k0, lA + wave * 512);
    gll16(pB + k0, lB + wave * 512);
    __syncthreads();
    short8v af[2], bfv[2];
    #pragma unroll
    for (int i = 0; i < 2; ++i)
      af[i] = *(const short8v*)(lA + (wm * 32 + i * 16 + lr) * 32 + rsw * 8);
    #pragma unroll
    for (int j = 0; j < 2; ++j)
      bfv[j] = *(const short8v*)(lB + (wn * 32 + j * 16 + lr) * 32 + rsw * 8);
    #pragma unroll
    for (int i = 0; i < 2; ++i)
      #pragma unroll
      for (int j = 0; j < 2; ++j)
        acc[i][j] = __builtin_amdgcn_mfma_f32_16x16x32_bf16(af[i], bfv[j], acc[i][j], 0, 0, 0);
  }

  #pragma unroll
  for (int i = 0; i < 2; ++i) {
    #pragma unroll
    for (int jj = 0; jj < 4; ++jj) {
      int row = m0 + wm * 32 + i * 16 + lq * 4 + jj;  // C/D: row=(l>>4)*4+reg, col=l&15
      if (row >= M) continue;
      #pragma unroll
      for (int j = 0; j < 2; ++j) {
        int col = n0 + wn * 32 + j * 16 + lr;
        float v = acc[i][j][jj];
        if (EPI == 1) {
          if (col < Nout) Cf[(size_t)row * Nout + col] = v + bias[col];
        } else {
          float o = v + bias[col] + xres[(size_t)row * 256 + col];
          Cb[(size_t)row * 256 + col] = (short)f2bfu(fmaxf(o, 0.f));
        }
      }
    }
  }
}

// ---------------- CSR scan / scatter ----------------

__global__ __launch_bounds__(1024) void scan_kernel(const int* __restrict__ deg,
                                                    int* __restrict__ rowptr,
                                                    int* __restrict__ cursor, int n) {
  __shared__ int part[1024];
  int t = threadIdx.x;
  int base = t * 20;
  int loc[20];
  int run = 0;
  #pragma unroll
  for (int j = 0; j < 20; ++j) {
    int idx = base + j;
    int v = (idx < n) ? deg[idx] : 0;
    loc[j] = run;
    run += v;
  }
  part[t] = run;
  __syncthreads();
  for (int off = 1; off < 1024; off <<= 1) {
    int add = (t >= off) ? part[t - off] : 0;
    __syncthreads();
    part[t] += add;
    __syncthreads();
  }
  int off0 = (t > 0) ? part[t - 1] : 0;
  #pragma unroll
  for (int j = 0; j < 20; ++j) {
    int idx = base + j;
    if (idx < n) {
      int v = off0 + loc[j];
      rowptr[idx] = v;
      cursor[idx] = v;
    }
  }
  if (t == 1023) rowptr[n] = part[1023];
}

__global__ void scatter_kernel(const int* __restrict__ ei, int* __restrict__ cursor,
                               int* __restrict__ csr_src, int E) {
  int e = blockIdx.x * 256 + threadIdx.x;
  if (e < E) {
    int pos = atomicAdd(&cursor[ei[E + e]], 1);
    csr_src[pos] = ei[e];
  }
}

// ---------------- fused softmax + z-aggregate (1 wave/dst, 8 heads, 4ch/lane) ----
__global__ __launch_bounds__(256) void alphaz_kernel(
    const short* __restrict__ x_bf, const float* __restrict__ a_s,
    const float* __restrict__ a_d, const float* __restrict__ ws_r,
    const int* __restrict__ rowptr, const int* __restrict__ csr,
    short* __restrict__ u, float* __restrict__ pp) {
  int d = blockIdx.x * 4 + (threadIdx.x >> 6);
  int lane = threadIdx.x & 63;
  int cl = lane * 4;
  int beg = rowptr[d];
  int deg = rowptr[d + 1] - beg;
  int nb = deg + 1;

  float ad8[8];
  ld8(a_d + (size_t)d * 8, ad8);

  float acc[8][4];
  #pragma unroll
  for (int h = 0; h < 8; ++h)
    #pragma unroll
    for (int c = 0; c < 4; ++c) acc[h][c] = 0.f;
  float s8[8] = {0, 0, 0, 0, 0, 0, 0, 0};

  for (int base = 0; base < nb; base += 64) {
    int i = base + lane;
    bool act = i < nb;
    int srcv = d;
    if (i < deg) srcv = csr[beg + i];
    float ex[8];
    {
      float t8[8];
      ld8(a_s + (size_t)srcv * 8, t8);
      #pragma unroll
      for (int h = 0; h < 8; ++h) {
        float e = t8[h] + ad8[h];
        e = (e > 0.f) ? e : 0.2f * e;
        float xx = act ? __expf(e) : 0.f;
        ex[h] = xx;
        s8[h] += xx;
      }
    }
    int cnt = nb - base;
    if (cnt > 64) cnt = 64;
    for (int e = 0; e < cnt; ++e) {
      int sb = __builtin_amdgcn_readlane(srcv, e);
      uint2 v = *(const uint2*)(x_bf + (size_t)sb * 256 + cl);
      float q[8];
      #pragma unroll
      for (int h = 0; h < 8; ++h) q[h] = bcast(ex[h], e);
      float xv0 = bfu_lo(v.x), xv1 = bfu_hi(v.x);
      float xv2 = bfu_lo(v.y), xv3 = bfu_hi(v.y);
      #pragma unroll
      for (int h = 0; h < 8; ++h) {
        acc[h][0] += q[h] * xv0;
        acc[h][1] += q[h] * xv1;
        acc[h][2] += q[h] * xv2;
        acc[h][3] += q[h] * xv3;
      }
    }
  }

  #pragma unroll
  for (int off = 1; off < 64; off <<= 1)
    #pragma unroll
    for (int h = 0; h < 8; ++h) s8[h] += __shfl_xor(s8[h], off);
  float inv[8];
  #pragma unroll
  for (int h = 0; h < 8; ++h) inv[h] = 1.f / (s8[h] + 1e-16f);

  #pragma unroll
  for (int h = 0; h < 8; ++h) {
    uint2 ov;
    ov.x = pack2(acc[h][0] * inv[h], acc[h][1] * inv[h]);
    ov.y = pack2(acc[h][2] * inv[h], acc[h][3] * inv[h]);
    *(uint2*)(u + (size_t)d * 2048 + h * 256 + cl) = ov;
  }

  float ppl[8] = {0, 0, 0, 0, 0, 0, 0, 0};
  {
    const float4* wr = (const float4*)(ws_r + (size_t)cl * 8);
    #pragma unroll
    for (int c = 0; c < 4; ++c) {
      float4 wa = wr[c * 2], wb = wr[c * 2 + 1];
      float zc[8];
      #pragma unroll
      for (int h = 0; h < 8; ++h) zc[h] = acc[h][c] * inv[h];
      ppl[0] += zc[0] * wa.x; ppl[1] += zc[1] * wa.y;
      ppl[2] += zc[2] * wa.z; ppl[3] += zc[3] * wa.w;
      ppl[4] += zc[4] * wb.x; ppl[5] += zc[5] * wb.y;
      ppl[6] += zc[6] * wb.z; ppl[7] += zc[7] * wb.w;
    }
  }
  #pragma unroll
  for (int off = 1; off < 64; off <<= 1)
    #pragma unroll
    for (int h = 0; h < 8; ++h) ppl[h] += __shfl_xor(ppl[h], off);
  if (lane == 0) {
    ((float4*)(pp + (size_t)d * 8))[0] = make_float4(ppl[0], ppl[1], ppl[2], ppl[3]);
    ((float4*)(pp + (size_t)d * 8))[1] = make_float4(ppl[4], ppl[5], ppl[6], ppl[7]);
  }
}

// ---------------- pooled reduction ----------------
__global__ __launch_bounds__(256) void reduce_pp_kernel(const float* __restrict__ pp,
                                                        float* __restrict__ pooled) {
  int tid = threadIdx.x;
  float loc[8] = {0, 0, 0, 0, 0, 0, 0, 0};
  for (int r = blockIdx.x * 256 + tid; r < 20000; r += 80 * 256) {
    float t[8];
    ld8(pp + (size_t)r * 8, t);
    #pragma unroll
    for (int h = 0; h < 8; ++h) loc[h] += t[h];
  }
  #pragma unroll
  for (int off = 1; off < 64; off <<= 1)
    #pragma unroll
    for (int h = 0; h < 8; ++h) loc[h] += __shfl_xor(loc[h], off);
  __shared__ float sred[4][8];
  int wave = tid >> 6, lane = tid & 63;
  if (lane == 0) {
    #pragma unroll
    for (int h = 0; h < 8; ++h) sred[wave][h] = loc[h];
  }
  __syncthreads();
  if (tid < 8) {
    atomicAdd(&pooled[tid], sred[0][tid] + sred[1][tid] + sred[2][tid] + sred[3][tid]);
  }
}

// ---------------- head softmax weights + fused bias ----------------
__global__ __launch_bounds__(256) void headwfb_kernel(const float* __restrict__ pooled,
    const float* __restrict__ b_gat, const float* __restrict__ conv_w,
    const float* __restrict__ conv_b, float* __restrict__ wsoft,
    float* __restrict__ fb) {
  __shared__ float sb[8];
  __shared__ float sw[8];
  int t = threadIdx.x;
  float v = 0.f;
  #pragma unroll
  for (int j = 0; j < 8; ++j) v += b_gat[t * 8 + j];
  #pragma unroll
  for (int off = 1; off < 32; off <<= 1) v += __shfl_xor(v, off);
  if ((t & 31) == 0) sb[t >> 5] = v;
  __syncthreads();
  if (t == 0) {
    const float invNC = 1.0f / (20000.0f * 256.0f);
    float g[8];
    float mx = -1e30f;
    #pragma unroll
    for (int h = 0; h < 8; ++h) {
      float pm = (pooled[h] + 20000.0f * sb[h]) * invNC;
      float gv = pm * conv_w[0] + conv_b[0];
      gv = fmaxf(gv, 0.f);
      g[h] = gv;
      mx = fmaxf(mx, gv);
    }
    float ssum = 0.f;
    #pragma unroll
    for (int h = 0; h < 8; ++h) { g[h] = __expf(g[h] - mx); ssum += g[h]; }
    #pragma unroll
    for (int h = 0; h < 8; ++h) {
      float w = g[h] / ssum;
      wsoft[h] = w;
      sw[h] = w;
    }
  }
  __syncthreads();
  float a = 0.f;
  #pragma unroll
  for (int h = 0; h < 8; ++h) a += sw[h] * b_gat[h * 256 + t];
  fb[t] = a;
}

// wmixT[c][h*256+k] = bf16(wsoft[h] * W_gat[k][h*256+c])
__global__ void wmix_kernel(const float* __restrict__ W, const float* __restrict__ wsoft,
                            short* __restrict__ out) {
  __shared__ float tile[32][33];
  int tx = threadIdx.x, ty = threadIdx.y;
  int h = blockIdx.z;
  float wh = wsoft[h];
  int c0 = blockIdx.x * 32, k0 = blockIdx.y * 32;
  #pragma unroll
  for (int j = ty; j < 32; j += 8)
    tile[j][tx] = W[(size_t)(k0 + j) * 2048 + h * 256 + c0 + tx];
  __syncthreads();
  #pragma unroll
  for (int j = ty; j < 32; j += 8)
    out[(size_t)(c0 + j) * 2048 + h * 256 + k0 + tx] = (short)f2bfu(wh * tile[tx][j]);
}

extern "C" void kernel_launch(void* const* d_in, const int* in_sizes, int n_in,
                              void* d_out, int out_size, void* d_ws, size_t ws_size,
                              hipStream_t stream) {
  (void)in_sizes; (void)n_in; (void)out_size; (void)ws_size;
  const float* x      = (const float*)d_in[0];
  const int*   ei     = (const int*)d_in[1];
  const float* W_gat  = (const float*)d_in[2];
  const float* att_s  = (const float*)d_in[3];
  const float* att_d  = (const float*)d_in[4];
  const float* b_gat  = (const float*)d_in[5];
  const float* conv_w = (const float*)d_in[6];
  const float* conv_b = (const float*)d_in[7];
  const float* W_lin  = (const float*)d_in[8];
  const float* b_lin  = (const float*)d_in[9];
  float* out = (float*)d_out;

  char* p = (char*)d_ws;
  size_t off = 0;
  auto alloc = [&](size_t bytes) -> void* {
    void* r = p + off;
    off = (off + bytes + 255) & ~(size_t)255;
    return r;
  };
  short* x_bf   = (short*)alloc((size_t)20000 * 256 * 2);  // reused as Hf
  short* wmixT  = (short*)alloc((size_t)256 * 2048 * 2);
  short* wlT    = (short*)alloc((size_t)256 * 256 * 2);
  float* ws_s   = (float*)alloc(2048 * 4);
  float* ws_d   = (float*)alloc(2048 * 4);
  float* ws_r   = (float*)alloc(2048 * 4);
  float* a_s    = (float*)alloc((size_t)20000 * 8 * 4);
  float* a_d    = (float*)alloc((size_t)20000 * 8 * 4);
  int*   deg    = (int*)alloc(20000 * 4);
  float* pooled = (float*)alloc(8 * 4);
  float* wsoft  = (float*)alloc(8 * 4);
  float* fb     = (float*)alloc(256 * 4);
  int*   rowptr = (int*)alloc(20001 * 4);
  int*   cursor = (int*)alloc(20000 * 4);
  int*   csr    = (int*)alloc(200000 * 4);
  float* pp     = (float*)alloc((size_t)20000 * 8 * 4);
  short* u      = (short*)alloc((size_t)20000 * 2048 * 2);
  short* Hf     = x_bf;  // x_bf dead after alphaz

  hipMemsetAsync(deg, 0, 20000 * 4, stream);
  hipMemsetAsync(pooled, 0, 8 * 4, stream);

  prep1_kernel<<<878, 256, 0, stream>>>(W_lin, wlT, W_gat, att_s, att_d,
                                        ws_s, ws_d, ws_r, ei, deg);
  scan_kernel<<<1, 1024, 0, stream>>>(deg, rowptr, cursor, 20000);
  asd_kernel<<<625, 256, 0, stream>>>(x, ws_s, ws_d, a_s, a_d, x_bf);
  scatter_kernel<<<782, 256, 0, stream>>>(ei, cursor, csr, 200000);
  alphaz_kernel<<<5000, 256, 0, stream>>>(x_bf, a_s, a_d, ws_r, rowptr, csr, u, pp);
  reduce_pp_kernel<<<80, 256, 0, stream>>>(pp, pooled);
  headwfb_kernel<<<1, 256, 0, stream>>>(pooled, b_gat, conv_w, conv_b, wsoft, fb);
  wmix_kernel<<<dim3(8, 8, 8), dim3(32, 8), 0, stream>>>(W_gat, wsoft, wmixT);
  // Hf = relu(u @ wmixT^T + fb + x), 64x64 tiles, XCD-mapped grid (320 i-slots x 4 j)
  gemm_kernel<2><<<1280, 256, 0, stream>>>(u, wmixT, 20000, 2048,
                                           Hf, nullptr, fb, x, 256);
  // out = Hf @ wlT^T + b_lin (Hf is L2/L3-hot)
  gemm_kernel<1><<<1280, 256, 0, stream>>>(Hf, wlT, 20000, 256,
                                           nullptr, out, b_lin, nullptr, 250);
}

// Round 16
// 175.031 us; speedup vs baseline: 1.1894x; 1.0645x over previous
//
#include <hip/hip_runtime.h>
#include <hip/hip_bf16.h>

// N=20000 nodes, E=200000 edges, H=8, C=256, IN=256, OUT=250, H*C=2048.
// R16: GEMM BK=64 (half the barriers per MFMA; conflict-free swizzle re-derived
//      for 128B rows: store chunk (l&7)^(l>>3), read (ks*4+lq)^(lr&7));
//      alphaz 1-wave blocks (20000 x 64 threads) for degree load-balance.

typedef __attribute__((ext_vector_type(8))) short short8v;
typedef __attribute__((ext_vector_type(4))) float float4v;

__device__ __forceinline__ unsigned f2bfu(float f) {
  unsigned u = __float_as_uint(f);
  return (u + 0x7fffu + ((u >> 16) & 1u)) >> 16;  // RNE f32 -> bf16
}
__device__ __forceinline__ float bfu_lo(unsigned u) { return __uint_as_float(u << 16); }
__device__ __forceinline__ float bfu_hi(unsigned u) { return __uint_as_float(u & 0xffff0000u); }
__device__ __forceinline__ unsigned pack2(float a, float b) { return f2bfu(a) | (f2bfu(b) << 16); }

__device__ __forceinline__ void ld8(const float* p, float* v) {
  float4 a = ((const float4*)p)[0], b = ((const float4*)p)[1];
  v[0] = a.x; v[1] = a.y; v[2] = a.z; v[3] = a.w;
  v[4] = b.x; v[5] = b.y; v[6] = b.z; v[7] = b.w;
}

__device__ __forceinline__ float bcast(float x, int e) {
  return __uint_as_float((unsigned)__builtin_amdgcn_readlane((int)__float_as_uint(x), e));
}

__device__ __forceinline__ void gll16(const void* g, void* l) {
  __builtin_amdgcn_global_load_lds(
      (__attribute__((address_space(1))) void*)const_cast<void*>(g),
      (__attribute__((address_space(3))) void*)(l), 16, 0, 0);
}

// ---------------- prep1: transpose(W_lin) + prepws + hist ----------------
__global__ __launch_bounds__(256) void prep1_kernel(
    const float* __restrict__ W_lin, short* __restrict__ wlT,
    const float* __restrict__ W, const float* __restrict__ att_s,
    const float* __restrict__ att_d, float* __restrict__ ws_s,
    float* __restrict__ ws_d, float* __restrict__ ws_r,
    const int* __restrict__ ei, int* __restrict__ deg) {
  __shared__ float smem[4096];
  int b = blockIdx.x;
  int t = threadIdx.x;
  if (b < 64) {
    float (*tile)[33] = (float(*)[33])smem;
    int tx = t & 31, ty = t >> 5;
    int c0 = (b & 7) * 32, r0 = (b >> 3) * 32;
    #pragma unroll
    for (int j = ty; j < 32; j += 8) {
      int r = r0 + j, c = c0 + tx;
      tile[j][tx] = (c < 250) ? W_lin[(size_t)r * 250 + c] : 0.f;
    }
    __syncthreads();
    #pragma unroll
    for (int j = ty; j < 32; j += 8) {
      int c = c0 + j, r = r0 + tx;
      wlT[(size_t)c * 256 + r] = (short)f2bfu(tile[tx][j]);
    }
  } else if (b < 96) {
    float* sas = smem;
    float* sad = smem + 2048;
    for (int i = t; i < 2048; i += 256) { sas[i] = att_s[i]; sad[i] = att_d[i]; }
    __syncthreads();
    int kk = t >> 5, h = (t >> 2) & 7, q = t & 3;
    int k = (b - 64) * 8 + kk;
    const float4* wr = (const float4*)(W + (size_t)k * 2048 + h * 256 + q * 64);
    const float* as = sas + h * 256 + q * 64;
    const float* ad = sad + h * 256 + q * 64;
    float s = 0.f, dd = 0.f, r = 0.f;
    #pragma unroll
    for (int c4 = 0; c4 < 16; ++c4) {
      float4 wv = wr[c4];
      int c = c4 * 4;
      s  += wv.x * as[c] + wv.y * as[c + 1] + wv.z * as[c + 2] + wv.w * as[c + 3];
      dd += wv.x * ad[c] + wv.y * ad[c + 1] + wv.z * ad[c + 2] + wv.w * ad[c + 3];
      r  += wv.x + wv.y + wv.z + wv.w;
    }
    #pragma unroll
    for (int off = 1; off < 4; off <<= 1) {
      s += __shfl_xor(s, off);
      dd += __shfl_xor(dd, off);
      r += __shfl_xor(r, off);
    }
    if (q == 0) {
      int g = k * 8 + h;
      ws_s[g] = s;
      ws_d[g] = dd;
      ws_r[g] = r;
    }
  } else {
    int e = (b - 96) * 256 + t;
    if (e < 200000) atomicAdd(&deg[ei[200000 + e]], 1);
  }
}

// a_s/a_d + coalesced x_bf (thread (node,h) owns chunks 8h..8h+7)
__global__ __launch_bounds__(256) void asd_kernel(const float* __restrict__ x,
    const float* __restrict__ ws_s, const float* __restrict__ ws_d,
    float* __restrict__ a_s, float* __restrict__ a_d, short* __restrict__ x_bf) {
  __shared__ float ls[2048], ld2[2048];
  int tid = threadIdx.x;
  for (int i = tid; i < 2048; i += 256) { ls[i] = ws_s[i]; ld2[i] = ws_d[i]; }
  __syncthreads();
  int node = blockIdx.x * 32 + (tid >> 3);
  int h = tid & 7;
  const float4* xr = (const float4*)(x + (size_t)node * 256);
  float as = 0.f, ad = 0.f;
  #pragma unroll 1
  for (int g = 0; g < 8; ++g) {
    bool own = (g == h);
    int bufi[16];
    #pragma unroll
    for (int j = 0; j < 8; ++j) {
      int k4 = g * 8 + j;
      float4 v = xr[k4];
      int k8 = k4 * 32 + h;
      as += v.x * ls[k8] + v.y * ls[k8 + 8] + v.z * ls[k8 + 16] + v.w * ls[k8 + 24];
      ad += v.x * ld2[k8] + v.y * ld2[k8 + 8] + v.z * ld2[k8 + 16] + v.w * ld2[k8 + 24];
      bufi[2 * j] = (int)pack2(v.x, v.y);
      bufi[2 * j + 1] = (int)pack2(v.z, v.w);
    }
    if (own) {
      int4* dst = (int4*)(x_bf + (size_t)node * 256 + h * 32);
      dst[0] = make_int4(bufi[0], bufi[1], bufi[2], bufi[3]);
      dst[1] = make_int4(bufi[4], bufi[5], bufi[6], bufi[7]);
      dst[2] = make_int4(bufi[8], bufi[9], bufi[10], bufi[11]);
      dst[3] = make_int4(bufi[12], bufi[13], bufi[14], bufi[15]);
    }
  }
  a_s[node * 8 + h] = as;
  a_d[node * 8 + h] = ad;
}

// ---------------- bf16 MFMA GEMM (64x64 tile, BK=64, XCD-mapped grid) ----------------
// Grid = 1280: g -> k=g&7, t=g>>3, i=k+8*(t>>2) [m-tile], j=t&3 [n-tile].
// LDS rows 128B. Store: lane l stages row (w*16+p*8+(l>>3)), phys chunk l&7 holds
// logical chunk (l&7)^(l>>3). Read: logical L=ks*4+lq at phys L^(lr&7). 2-way = free.
template <int EPI>
__global__ __launch_bounds__(256, 4) void gemm_kernel(
    const short* __restrict__ A, const short* __restrict__ BT,
    int M, int K,
    short* __restrict__ Cb, float* __restrict__ Cf,
    const float* __restrict__ bias, const float* __restrict__ xres, int Nout) {
  int g = blockIdx.x;
  int xk = g & 7, tt = g >> 3;
  int it = xk + 8 * (tt >> 2);
  if (it >= ((M + 63) >> 6)) return;
  int m0 = it << 6;
  int n0 = (tt & 3) << 6;

  __shared__ short lA[64 * 64];   // 8 KB
  __shared__ short lB[64 * 64];   // 8 KB
  int tid = threadIdx.x;
  int wave = tid >> 6, lane = tid & 63;
  int wm = wave >> 1, wn = wave & 1;
  int lr = lane & 15, lq = lane >> 4;

  float4v acc[2][2];
  #pragma unroll
  for (int i = 0; i < 2; ++i)
    #pragma unroll
    for (int j = 0; j < 2; ++j) acc[i][j] = (float4v){0.f, 0.f, 0.f, 0.f};

  // staging: pass p (0,1): lane stages row w*16 + p*8 + (l>>3), 16B chunk l&7
  int lc = (lane & 7) ^ (lane >> 3);   // logical chunk staged by this lane
  const short* pA[2];
  const short* pB[2];
  #pragma unroll
  for (int p = 0; p < 2; ++p) {
    int rl = wave * 16 + p * 8 + (lane >> 3);
    int ar = m0 + rl;
    if (ar >= M) ar = M - 1;
    pA[p] = A + (size_t)ar * K + lc * 8;
    pB[p] = BT + (size_t)(n0 + rl) * K + lc * 8;
  }

  for (int k0 = 0; k0 < K; k0 += 64) {
    __syncthreads();
    #pragma unroll
    for (int p = 0; p < 2; ++p) {
      gll16(pA[p] + k0, lA + (wave * 16 + p * 8) * 64);
      gll16(pB[p] + k0, lB + (wave * 16 + p * 8) * 64);
    }
    __syncthreads();
    #pragma unroll
    for (int ks = 0; ks < 2; ++ks) {
      int phys = (((ks * 4 + lq) ^ (lr & 7))) * 8;
      short8v af[2], bfv[2];
      #pragma unroll
      for (int i = 0; i < 2; ++i)
        af[i] = *(const short8v*)(lA + (wm * 32 + i * 16 + lr) * 64 + phys);
      #pragma unroll
      for (int j = 0; j < 2; ++j)
        bfv[j] = *(const short8v*)(lB + (wn * 32 + j * 16 + lr) * 64 + phys);
      #pragma unroll
      for (int i = 0; i < 2; ++i)
        #pragma unroll
        for (int j = 0; j < 2; ++j)
          acc[i][j] = __builtin_amdgcn_mfma_f32_16x16x32_bf16(af[i], bfv[j], acc[i][j], 0, 0, 0);
    }
  }

  #pragma unroll
  for (int i = 0; i < 2; ++i) {
    #pragma unroll
    for (int jj = 0; jj < 4; ++jj) {
      int row = m0 + wm * 32 + i * 16 + lq * 4 + jj;  // C/D: row=(l>>4)*4+reg, col=l&15
      if (row >= M) continue;
      #pragma unroll
      for (int j = 0; j < 2; ++j) {
        int col = n0 + wn * 32 + j * 16 + lr;
        float v = acc[i][j][jj];
        if (EPI == 1) {
          if (col < Nout) Cf[(size_t)row * Nout + col] = v + bias[col];
        } else {
          float o = v + bias[col] + xres[(size_t)row * 256 + col];
          Cb[(size_t)row * 256 + col] = (short)f2bfu(fmaxf(o, 0.f));
        }
      }
    }
  }
}

// ---------------- CSR scan / scatter ----------------

__global__ __launch_bounds__(1024) void scan_kernel(const int* __restrict__ deg,
                                                    int* __restrict__ rowptr,
                                                    int* __restrict__ cursor, int n) {
  __shared__ int part[1024];
  int t = threadIdx.x;
  int base = t * 20;
  int loc[20];
  int run = 0;
  #pragma unroll
  for (int j = 0; j < 20; ++j) {
    int idx = base + j;
    int v = (idx < n) ? deg[idx] : 0;
    loc[j] = run;
    run += v;
  }
  part[t] = run;
  __syncthreads();
  for (int off = 1; off < 1024; off <<= 1) {
    int add = (t >= off) ? part[t - off] : 0;
    __syncthreads();
    part[t] += add;
    __syncthreads();
  }
  int off0 = (t > 0) ? part[t - 1] : 0;
  #pragma unroll
  for (int j = 0; j < 20; ++j) {
    int idx = base + j;
    if (idx < n) {
      int v = off0 + loc[j];
      rowptr[idx] = v;
      cursor[idx] = v;
    }
  }
  if (t == 1023) rowptr[n] = part[1023];
}

__global__ void scatter_kernel(const int* __restrict__ ei, int* __restrict__ cursor,
                               int* __restrict__ csr_src, int E) {
  int e = blockIdx.x * 256 + threadIdx.x;
  if (e < E) {
    int pos = atomicAdd(&cursor[ei[E + e]], 1);
    csr_src[pos] = ei[e];
  }
}

// ---------------- fused softmax + z-aggregate (1 wave = 1 dst; 8 heads, 4ch/lane) ----
__global__ __launch_bounds__(64) void alphaz_kernel(
    const short* __restrict__ x_bf, const float* __restrict__ a_s,
    const float* __restrict__ a_d, const float* __restrict__ ws_r,
    const int* __restrict__ rowptr, const int* __restrict__ csr,
    short* __restrict__ u, float* __restrict__ pp) {
  int d = blockIdx.x;
  int lane = threadIdx.x;
  int cl = lane * 4;
  int beg = rowptr[d];
  int deg = rowptr[d + 1] - beg;
  int nb = deg + 1;

  float ad8[8];
  ld8(a_d + (size_t)d * 8, ad8);

  float acc[8][4];
  #pragma unroll
  for (int h = 0; h < 8; ++h)
    #pragma unroll
    for (int c = 0; c < 4; ++c) acc[h][c] = 0.f;
  float s8[8] = {0, 0, 0, 0, 0, 0, 0, 0};

  for (int base = 0; base < nb; base += 64) {
    int i = base + lane;
    bool act = i < nb;
    int srcv = d;
    if (i < deg) srcv = csr[beg + i];
    float ex[8];
    {
      float t8[8];
      ld8(a_s + (size_t)srcv * 8, t8);
      #pragma unroll
      for (int h = 0; h < 8; ++h) {
        float e = t8[h] + ad8[h];
        e = (e > 0.f) ? e : 0.2f * e;
        float xx = act ? __expf(e) : 0.f;
        ex[h] = xx;
        s8[h] += xx;
      }
    }
    int cnt = nb - base;
    if (cnt > 64) cnt = 64;
    for (int e = 0; e < cnt; ++e) {
      int sb = __builtin_amdgcn_readlane(srcv, e);
      uint2 v = *(const uint2*)(x_bf + (size_t)sb * 256 + cl);
      float q[8];
      #pragma unroll
      for (int h = 0; h < 8; ++h) q[h] = bcast(ex[h], e);
      float xv0 = bfu_lo(v.x), xv1 = bfu_hi(v.x);
      float xv2 = bfu_lo(v.y), xv3 = bfu_hi(v.y);
      #pragma unroll
      for (int h = 0; h < 8; ++h) {
        acc[h][0] += q[h] * xv0;
        acc[h][1] += q[h] * xv1;
        acc[h][2] += q[h] * xv2;
        acc[h][3] += q[h] * xv3;
      }
    }
  }

  #pragma unroll
  for (int off = 1; off < 64; off <<= 1)
    #pragma unroll
    for (int h = 0; h < 8; ++h) s8[h] += __shfl_xor(s8[h], off);
  float inv[8];
  #pragma unroll
  for (int h = 0; h < 8; ++h) inv[h] = 1.f / (s8[h] + 1e-16f);

  #pragma unroll
  for (int h = 0; h < 8; ++h) {
    uint2 ov;
    ov.x = pack2(acc[h][0] * inv[h], acc[h][1] * inv[h]);
    ov.y = pack2(acc[h][2] * inv[h], acc[h][3] * inv[h]);
    *(uint2*)(u + (size_t)d * 2048 + h * 256 + cl) = ov;
  }

  float ppl[8] = {0, 0, 0, 0, 0, 0, 0, 0};
  {
    const float4* wr = (const float4*)(ws_r + (size_t)cl * 8);
    #pragma unroll
    for (int c = 0; c < 4; ++c) {
      float4 wa = wr[c * 2], wb = wr[c * 2 + 1];
      float zc[8];
      #pragma unroll
      for (int h = 0; h < 8; ++h) zc[h] = acc[h][c] * inv[h];
      ppl[0] += zc[0] * wa.x; ppl[1] += zc[1] * wa.y;
      ppl[2] += zc[2] * wa.z; ppl[3] += zc[3] * wa.w;
      ppl[4] += zc[4] * wb.x; ppl[5] += zc[5] * wb.y;
      ppl[6] += zc[6] * wb.z; ppl[7] += zc[7] * wb.w;
    }
  }
  #pragma unroll
  for (int off = 1; off < 64; off <<= 1)
    #pragma unroll
    for (int h = 0; h < 8; ++h) ppl[h] += __shfl_xor(ppl[h], off);
  if (lane == 0) {
    ((float4*)(pp + (size_t)d * 8))[0] = make_float4(ppl[0], ppl[1], ppl[2], ppl[3]);
    ((float4*)(pp + (size_t)d * 8))[1] = make_float4(ppl[4], ppl[5], ppl[6], ppl[7]);
  }
}

// ---------------- pooled reduction ----------------
__global__ __launch_bounds__(256) void reduce_pp_kernel(const float* __restrict__ pp,
                                                        float* __restrict__ pooled) {
  int tid = threadIdx.x;
  float loc[8] = {0, 0, 0, 0, 0, 0, 0, 0};
  for (int r = blockIdx.x * 256 + tid; r < 20000; r += 80 * 256) {
    float t[8];
    ld8(pp + (size_t)r * 8, t);
    #pragma unroll
    for (int h = 0; h < 8; ++h) loc[h] += t[h];
  }
  #pragma unroll
  for (int off = 1; off < 64; off <<= 1)
    #pragma unroll
    for (int h = 0; h < 8; ++h) loc[h] += __shfl_xor(loc[h], off);
  __shared__ float sred[4][8];
  int wave = tid >> 6, lane = tid & 63;
  if (lane == 0) {
    #pragma unroll
    for (int h = 0; h < 8; ++h) sred[wave][h] = loc[h];
  }
  __syncthreads();
  if (tid < 8) {
    atomicAdd(&pooled[tid], sred[0][tid] + sred[1][tid] + sred[2][tid] + sred[3][tid]);
  }
}

// ---------------- head softmax weights + fused bias ----------------
__global__ __launch_bounds__(256) void headwfb_kernel(const float* __restrict__ pooled,
    const float* __restrict__ b_gat, const float* __restrict__ conv_w,
    const float* __restrict__ conv_b, float* __restrict__ wsoft,
    float* __restrict__ fb) {
  __shared__ float sb[8];
  __shared__ float sw[8];
  int t = threadIdx.x;
  float v = 0.f;
  #pragma unroll
  for (int j = 0; j < 8; ++j) v += b_gat[t * 8 + j];
  #pragma unroll
  for (int off = 1; off < 32; off <<= 1) v += __shfl_xor(v, off);
  if ((t & 31) == 0) sb[t >> 5] = v;
  __syncthreads();
  if (t == 0) {
    const float invNC = 1.0f / (20000.0f * 256.0f);
    float g[8];
    float mx = -1e30f;
    #pragma unroll
    for (int h = 0; h < 8; ++h) {
      float pm = (pooled[h] + 20000.0f * sb[h]) * invNC;
      float gv = pm * conv_w[0] + conv_b[0];
      gv = fmaxf(gv, 0.f);
      g[h] = gv;
      mx = fmaxf(mx, gv);
    }
    float ssum = 0.f;
    #pragma unroll
    for (int h = 0; h < 8; ++h) { g[h] = __expf(g[h] - mx); ssum += g[h]; }
    #pragma unroll
    for (int h = 0; h < 8; ++h) {
      float w = g[h] / ssum;
      wsoft[h] = w;
      sw[h] = w;
    }
  }
  __syncthreads();
  float a = 0.f;
  #pragma unroll
  for (int h = 0; h < 8; ++h) a += sw[h] * b_gat[h * 256 + t];
  fb[t] = a;
}

// wmixT[c][h*256+k] = bf16(wsoft[h] * W_gat[k][h*256+c])
__global__ void wmix_kernel(const float* __restrict__ W, const float* __restrict__ wsoft,
                            short* __restrict__ out) {
  __shared__ float tile[32][33];
  int tx = threadIdx.x, ty = threadIdx.y;
  int h = blockIdx.z;
  float wh = wsoft[h];
  int c0 = blockIdx.x * 32, k0 = blockIdx.y * 32;
  #pragma unroll
  for (int j = ty; j < 32; j += 8)
    tile[j][tx] = W[(size_t)(k0 + j) * 2048 + h * 256 + c0 + tx];
  __syncthreads();
  #pragma unroll
  for (int j = ty; j < 32; j += 8)
    out[(size_t)(c0 + j) * 2048 + h * 256 + k0 + tx] = (short)f2bfu(wh * tile[tx][j]);
}

extern "C" void kernel_launch(void* const* d_in, const int* in_sizes, int n_in,
                              void* d_out, int out_size, void* d_ws, size_t ws_size,
                              hipStream_t stream) {
  (void)in_sizes; (void)n_in; (void)out_size; (void)ws_size;
  const float* x      = (const float*)d_in[0];
  const int*   ei     = (const int*)d_in[1];
  const float* W_gat  = (const float*)d_in[2];
  const float* att_s  = (const float*)d_in[3];
  const float* att_d  = (const float*)d_in[4];
  const float* b_gat  = (const float*)d_in[5];
  const float* conv_w = (const float*)d_in[6];
  const float* conv_b = (const float*)d_in[7];
  const float* W_lin  = (const float*)d_in[8];
  const float* b_lin  = (const float*)d_in[9];
  float* out = (float*)d_out;

  char* p = (char*)d_ws;
  size_t off = 0;
  auto alloc = [&](size_t bytes) -> void* {
    void* r = p + off;
    off = (off + bytes + 255) & ~(size_t)255;
    return r;
  };
  short* x_bf   = (short*)alloc((size_t)20000 * 256 * 2);  // reused as Hf
  short* wmixT  = (short*)alloc((size_t)256 * 2048 * 2);
  short* wlT    = (short*)alloc((size_t)256 * 256 * 2);
  float* ws_s   = (float*)alloc(2048 * 4);
  float* ws_d   = (float*)alloc(2048 * 4);
  float* ws_r   = (float*)alloc(2048 * 4);
  float* a_s    = (float*)alloc((size_t)20000 * 8 * 4);
  float* a_d    = (float*)alloc((size_t)20000 * 8 * 4);
  int*   deg    = (int*)alloc(20000 * 4);
  float* pooled = (float*)alloc(8 * 4);
  float* wsoft  = (float*)alloc(8 * 4);
  float* fb     = (float*)alloc(256 * 4);
  int*   rowptr = (int*)alloc(20001 * 4);
  int*   cursor = (int*)alloc(20000 * 4);
  int*   csr    = (int*)alloc(200000 * 4);
  float* pp     = (float*)alloc((size_t)20000 * 8 * 4);
  short* u      = (short*)alloc((size_t)20000 * 2048 * 2);
  short* Hf     = x_bf;  // x_bf dead after alphaz

  hipMemsetAsync(deg, 0, 20000 * 4, stream);
  hipMemsetAsync(pooled, 0, 8 * 4, stream);

  prep1_kernel<<<878, 256, 0, stream>>>(W_lin, wlT, W_gat, att_s, att_d,
                                        ws_s, ws_d, ws_r, ei, deg);
  scan_kernel<<<1, 1024, 0, stream>>>(deg, rowptr, cursor, 20000);
  asd_kernel<<<625, 256, 0, stream>>>(x, ws_s, ws_d, a_s, a_d, x_bf);
  scatter_kernel<<<782, 256, 0, stream>>>(ei, cursor, csr, 200000);
  alphaz_kernel<<<20000, 64, 0, stream>>>(x_bf, a_s, a_d, ws_r, rowptr, csr, u, pp);
  reduce_pp_kernel<<<80, 256, 0, stream>>>(pp, pooled);
  headwfb_kernel<<<1, 256, 0, stream>>>(pooled, b_gat, conv_w, conv_b, wsoft, fb);
  wmix_kernel<<<dim3(8, 8, 8), dim3(32, 8), 0, stream>>>(W_gat, wsoft, wmixT);
  // Hf = relu(u @ wmixT^T + fb + x), 64x64 tiles, BK=64, XCD-mapped grid
  gemm_kernel<2><<<1280, 256, 0, stream>>>(u, wmixT, 20000, 2048,
                                           Hf, nullptr, fb, x, 256);
  // out = Hf @ wlT^T + b_lin (Hf is L2/L3-hot)
  gemm_kernel<1><<<1280, 256, 0, stream>>>(Hf, wlT, 20000, 256,
                                           nullptr, out, b_lin, nullptr, 250);
}